// Round 3
// baseline (37875.412 us; speedup 1.0000x reference)
//
#include <hip/hip_runtime.h>
#include <math.h>

#define NFEAT 128
#define NH 255
#define NP 256
#define NI 254
#define NBATCH 128
#define EPSQ 1e-4f
#define NITER 20
#define SIGMA 0.1f
#define BLOCK 512
#define KBCH 8
#define KLSIZE 33280   /* packed lower triangle, rows padded to 4-float alignment */
#define SMEM_FLOATS (KLSIZE + KBCH*256 + 15*256 + 64)
#define SMEM_BYTES (SMEM_FLOATS*4)

// padded packed lower-triangle index: row i starts at 4*(a+1)*(2a+b), a=i>>2, b=i&3
__device__ __forceinline__ int IDX(int i, int j){
  int a = i >> 2, bb = i & 3;
  return 4*(a+1)*(2*a + bb) + j;
}
__device__ __forceinline__ float clampf(float x, float m){
  // also scrubs NaN -> -m (fmaxf/fminf return the non-NaN operand)
  return fminf(fmaxf(x, -m), m);
}

// ---------------- setup kernels (read L/W directly; minimal workspace) ----------------
__global__ void k_setupQ(const float* __restrict__ L, float* __restrict__ Q){
  int i = blockIdx.x, j = threadIdx.x;
  float acc;
  if (i < NH && j < NH){
    int kmax = (i < j) ? i : j;
    acc = 0.0f;
    for (int k = 0; k <= kmax; ++k) acc = fmaf(L[i*NH + k], L[j*NH + k], acc);
    if (i == j) acc += EPSQ;
  } else {
    acc = (i == j) ? 1.0f : 0.0f;   // padded row/col 255 = e255
  }
  Q[i*NP + j] = acc;
}
__global__ void k_setupP(const float* __restrict__ x, const float* __restrict__ W,
                         const float* __restrict__ bias, float* __restrict__ P){
  int b = blockIdx.x, j = threadIdx.x;
  float acc = 0.0f;
  if (j < NH){
    acc = bias[j];
    for (int f = 0; f < NFEAT; ++f) acc = fmaf(x[b*NFEAT + f], W[j*NFEAT + f], acc);
  }
  P[b*NP + j] = acc;
}
__global__ void k_setupH(const float* __restrict__ G, const float* __restrict__ z0,
                         const float* __restrict__ s0, float* __restrict__ H){
  int k = threadIdx.x;
  float acc = 0.0f;
  if (k < NI){
    acc = s0[k];
    for (int i = 0; i < NH; ++i) acc = fmaf(G[k*NH + i], z0[i], acc);
  }
  H[k] = acc;
}

// ---------------- main QP kernel: one block per batch row ----------------
__global__ void __launch_bounds__(BLOCK) qp_kernel(
    const float* __restrict__ Qg, const float* __restrict__ G,
    const float* __restrict__ Pg, const float* __restrict__ Hg,
    float* __restrict__ out)
{
  extern __shared__ float sm[];
  float* Kl   = sm;                 // 33280
  float* gb   = Kl + KLSIZE;        // KBCH*256
  float* zv   = gb + KBCH*256;
  float* sv   = zv + NP;
  float* lv   = sv + NP;
  float* psh  = lv + NP;
  float* hsh  = psh + NP;
  float* r1   = hsh + NP;
  float* r2   = r1 + NP;
  float* r3   = r2 + NP;
  float* dd   = r3 + NP;
  float* wwv  = dd + NP;
  float* dsv  = wwv + NP;
  float* dlv  = dsv + NP;
  float* yv   = dlv + NP;
  float* invd = yv + NP;
  float* dscv = invd + NP;
  float* misc = dscv + NP;          // 64

  const int tid  = threadIdx.x;
  const int lane = tid & 63;
  const int wv   = tid >> 6;
  const int b    = blockIdx.x;

  // ---- zero ALL of LDS: padding slots of the packed triangle stay 0 forever,
  // so every float4 over-read is benign by construction ----
  for (int i = tid; i < SMEM_FLOATS; i += BLOCK) sm[i] = 0.0f;
  __syncthreads();

  // ---- static mappings ----
  // off-diagonal 8x8 K tiles: tid<496 -> (tr,tc), tr in 1..31, tc<tr
  int ktr = 0, ktc = 0;
  if (tid < 496){
    int t = tid;
    int r = (int)((sqrtf(8.0f*(float)t + 1.0f) + 1.0f)*0.5f);
    while (r*(r-1)/2 > t) --r;
    while ((r+1)*r/2 <= t) ++r;
    ktr = r; ktc = t - r*(r-1)/2;
  }
  const int i0 = ktr*8, j0k = ktc*8;

  // diagonal-tile elements (32 tiles x 36 elems = 1152), up to 3 per thread
  int dI[3], dJ[3];
  #pragma unroll
  for (int q = 0; q < 3; ++q){
    int e = tid + 512*q;
    if (e < 1152){
      int dt = e/36, e36 = e - dt*36;
      int r = (int)((sqrtf(8.0f*(float)e36 + 1.0f) - 1.0f)*0.5f);
      while (r*(r+1)/2 > e36) --r;
      while ((r+1)*(r+2)/2 <= e36) ++r;
      int c = e36 - r*(r+1)/2;
      dI[q] = dt*8 + r; dJ[q] = dt*8 + c;
    } else { dI[q] = -1; dJ[q] = 0; }
  }

  // ---- init state ----
  for (int i = tid; i < NP; i += BLOCK){
    zv[i] = 0.0f;
    sv[i] = 1.0f;
    lv[i] = (i < NI) ? 1.0f : 0.0f;
    psh[i] = Pg[b*NP + i];
    hsh[i] = Hg[i];
  }
  __syncthreads();

  for (int it = 0; it < NITER; ++it){
    // ---- A1: r1 = Q z (wave-per-row, 2 rows at a time) ----
    {
      int ib0 = wv*32;
      float z0l = zv[lane], z1l = zv[lane+64], z2l = zv[lane+128], z3l = zv[lane+192];
      for (int i = ib0; i < ib0 + 32; i += 2){
        const float* q0 = Qg + i*NP;
        const float* q1 = q0 + NP;
        float v0 = q0[lane]*z0l + q0[lane+64]*z1l + q0[lane+128]*z2l + q0[lane+192]*z3l;
        float v1 = q1[lane]*z0l + q1[lane+64]*z1l + q1[lane+128]*z2l + q1[lane+192]*z3l;
        #pragma unroll
        for (int m = 32; m >= 1; m >>= 1){ v0 += __shfl_xor(v0, m, 64); v1 += __shfl_xor(v1, m, 64); }
        if (lane == 0){ r1[i] = v0; r1[i+1] = v1; }
      }
    }
    // ---- A2: G^T lam partials ----
    {
      int i  = tid & 255;
      int k0 = (tid < 256) ? 0 : 127;
      int k1 = (tid < 256) ? 127 : NI;
      float acc = 0.0f;
      if (i < NH){
        const float* gp = G + k0*NH + i;
        #pragma unroll 4
        for (int k = k0; k < k1; ++k){ acc = fmaf(*gp, lv[k], acc); gp += NH; }
      }
      if (tid < 256) dsv[i] = acc; else dlv[i] = acc;
    }
    __syncthreads();
    // ---- A3: combine r1 ----
    if (tid < NP) r1[tid] = r1[tid] + psh[tid] + dsv[tid] + dlv[tid];
    // ---- B: r2 = G z + s - h (wave-per-row) ----
    {
      int kb = wv*32, ke = min(kb + 32, NI);
      float z0l = zv[lane], z1l = zv[lane+64], z2l = zv[lane+128];
      float z3l = (lane < 63) ? zv[lane+192] : 0.0f;
      for (int k = kb; k < ke; k += 2){
        const float* g0 = G + k*NH;
        const float* g1 = g0 + NH;
        float a3 = (lane < 63) ? g0[lane+192] : 0.0f;
        float b3 = (lane < 63) ? g1[lane+192] : 0.0f;
        float v0 = g0[lane]*z0l + g0[lane+64]*z1l + g0[lane+128]*z2l + a3*z3l;
        float v1 = g1[lane]*z0l + g1[lane+64]*z1l + g1[lane+128]*z2l + b3*z3l;
        #pragma unroll
        for (int m = 32; m >= 1; m >>= 1){ v0 += __shfl_xor(v0, m, 64); v1 += __shfl_xor(v1, m, 64); }
        if (lane == 0){
          r2[k]   = v0 + sv[k]   - hsh[k];
          r2[k+1] = v1 + sv[k+1] - hsh[k+1];
        }
      }
    }
    __syncthreads();
    // ---- C: mu, r3, d, w ----
    {
      float sl = (tid < NI) ? sv[tid]*lv[tid] : 0.0f;
      #pragma unroll
      for (int m = 32; m >= 1; m >>= 1) sl += __shfl_xor(sl, m, 64);
      if (lane == 0) misc[wv] = sl;
    }
    __syncthreads();
    if (tid == 0){
      float t = 0.0f;
      #pragma unroll
      for (int q = 0; q < 8; ++q) t += misc[q];
      misc[17] = SIGMA * (t * (1.0f/(float)NI));
    }
    __syncthreads();
    if (tid < NI){
      float sk = sv[tid], lk = lv[tid];
      float skg = fmaxf(sk, 1e-30f);                 // FTZ guard
      float r3k = sk*lk - misc[17];
      r3[tid] = r3k;
      dd[tid] = fminf(lk/skg, 1e24f);                // keep K build finite
      wwv[tid] = clampf((lk*r2[tid] - r3k)/skg, 1e30f);
    }
    __syncthreads();
    // ---- D0: K diagonal -> Jacobi equilibration scale dscv ----
    {
      int i  = tid & 255;
      int k0 = (tid < 256) ? 0 : 127;
      int k1 = (tid < 256) ? 127 : NI;
      float acc = 0.0f;
      if (i < NH){
        const float* gp = G + k0*NH + i;
        #pragma unroll 4
        for (int k = k0; k < k1; ++k){ float g = *gp; acc = fmaf(dd[k]*g, g, acc); gp += NH; }
      }
      if (tid < 256) dsv[i] = acc; else dlv[i] = acc;
    }
    __syncthreads();
    if (tid < NP){
      float diag = Qg[tid*NP + tid] + dsv[tid] + dlv[tid];
      dscv[tid] = rsqrtf(fmaxf(diag, 1e-12f));
    }
    __syncthreads();
    // ---- D: rhs = -(r1 + w @ G); scaled rhs~ = dsc * rhs -> yv ----
    {
      int i  = tid & 255;
      int k0 = (tid < 256) ? 0 : 127;
      int k1 = (tid < 256) ? 127 : NI;
      float acc = 0.0f;
      if (i < NH){
        const float* gp = G + k0*NH + i;
        #pragma unroll 4
        for (int k = k0; k < k1; ++k){ acc = fmaf(*gp, wwv[k], acc); gp += NH; }
      }
      if (tid < 256) dsv[i] = acc; else dlv[i] = acc;
    }
    __syncthreads();
    if (tid < NP) yv[tid] = -(r1[tid] + dsv[tid] + dlv[tid]) * dscv[tid];

    // ---- E: K~ = S(Q + G^T D G)S packed lower triangle in LDS ----
    // Scaled SPD with unit diagonal => all entries in [-1,1], |L~| <= 1: no overflow.
    float accT[64];
    if (tid < 496){
      #pragma unroll
      for (int r = 0; r < 8; ++r){
        float4 qa = *reinterpret_cast<const float4*>(&Qg[(i0+r)*NP + j0k]);
        float4 qb = *reinterpret_cast<const float4*>(&Qg[(i0+r)*NP + j0k + 4]);
        accT[r*8+0]=qa.x; accT[r*8+1]=qa.y; accT[r*8+2]=qa.z; accT[r*8+3]=qa.w;
        accT[r*8+4]=qb.x; accT[r*8+5]=qb.y; accT[r*8+6]=qb.z; accT[r*8+7]=qb.w;
      }
    }
    float accD[3];
    #pragma unroll
    for (int q = 0; q < 3; ++q) accD[q] = (dI[q] >= 0) ? Qg[dI[q]*NP + dJ[q]] : 0.0f;

    for (int c0 = 0; c0 < NP; c0 += KBCH){
      __syncthreads();
      { // stage sqrt(d[k]) * G[k][:] rows c0..c0+7 (zero-padded)
        int base = tid*4;
        int kk = base >> 8;
        int j  = base & 255;
        int krow = c0 + kk;
        float4 v; v.x = v.y = v.z = v.w = 0.0f;
        if (krow < NI){
          float sd = sqrtf(dd[krow]);
          const float* gr = G + krow*NH + j;
          v.x = gr[0]*sd;
          v.y = gr[1]*sd;
          v.z = gr[2]*sd;
          v.w = (j + 3 < NH) ? gr[3]*sd : 0.0f;
        }
        *reinterpret_cast<float4*>(&gb[base]) = v;
      }
      __syncthreads();
      #pragma unroll
      for (int kk = 0; kk < KBCH; ++kk){
        const float* gr = gb + kk*256;
        #pragma unroll
        for (int q = 0; q < 3; ++q)
          if (dI[q] >= 0) accD[q] = fmaf(gr[dI[q]], gr[dJ[q]], accD[q]);
        if (tid < 496){
          float4 a0 = *reinterpret_cast<const float4*>(&gr[i0]);
          float4 a1 = *reinterpret_cast<const float4*>(&gr[i0+4]);
          float4 b0 = *reinterpret_cast<const float4*>(&gr[j0k]);
          float4 b1 = *reinterpret_cast<const float4*>(&gr[j0k+4]);
          float gi[8] = {a0.x,a0.y,a0.z,a0.w,a1.x,a1.y,a1.z,a1.w};
          float gj[8] = {b0.x,b0.y,b0.z,b0.w,b1.x,b1.y,b1.z,b1.w};
          #pragma unroll
          for (int r = 0; r < 8; ++r){
            #pragma unroll
            for (int c = 0; c < 8; ++c) accT[r*8+c] = fmaf(gi[r], gj[c], accT[r*8+c]);
          }
        }
      }
    }
    __syncthreads();
    if (tid < 496){
      float sj[8];
      #pragma unroll
      for (int c = 0; c < 8; ++c) sj[c] = dscv[j0k + c];
      #pragma unroll
      for (int r = 0; r < 8; ++r){
        float sr = dscv[i0 + r];
        int rb = IDX(i0+r, j0k);
        float4 v0, v1;
        v0.x=accT[r*8+0]*sr*sj[0]; v0.y=accT[r*8+1]*sr*sj[1];
        v0.z=accT[r*8+2]*sr*sj[2]; v0.w=accT[r*8+3]*sr*sj[3];
        v1.x=accT[r*8+4]*sr*sj[4]; v1.y=accT[r*8+5]*sr*sj[5];
        v1.z=accT[r*8+6]*sr*sj[6]; v1.w=accT[r*8+7]*sr*sj[7];
        *reinterpret_cast<float4*>(&Kl[rb])   = v0;
        *reinterpret_cast<float4*>(&Kl[rb+4]) = v1;
      }
    }
    #pragma unroll
    for (int q = 0; q < 3; ++q)
      if (dI[q] >= 0) Kl[IDX(dI[q], dJ[q])] = accD[q]*dscv[dI[q]]*dscv[dJ[q]];
    __syncthreads();

    // ---- F: blocked Cholesky (NB=16) on K~ (row 255 = e255 stays inert) ----
    for (int pan = 0; pan < 16; ++pan){
      int j0 = pan*16;
      // 16x16 diag factor: single wave, all-register, shuffle-based.
      if (tid < 64){
        int r = lane & 15;
        int rb = IDX(j0 + r, j0);
        float a[16];
        #pragma unroll
        for (int qq = 0; qq < 4; ++qq){
          float4 v = *reinterpret_cast<const float4*>(&Kl[rb + 4*qq]);
          a[4*qq+0]=v.x; a[4*qq+1]=v.y; a[4*qq+2]=v.z; a[4*qq+3]=v.w;
        }
        #pragma unroll
        for (int j = 0; j < 16; ++j){
          float dj = __shfl(a[j], j);              // updated A[j][j] from lane j
          dj = (dj > 1e-8f) ? dj : 1e-8f;          // relative pivot floor (scrubs NaN)
          float piv = sqrtf(dj);
          float inv = 1.0f/piv;
          float lrj = clampf(a[j]*inv, 4.0f);      // |L~| <= 1 in exact arithmetic
          a[j] = (r == j) ? piv : lrj;
          if (lane == j) invd[j0+j] = inv;
          #pragma unroll
          for (int c = j+1; c < 16; ++c){
            float lcj = __shfl(a[j], c);           // L[c][j] from lane c
            a[c] = fmaf(-a[j], lcj, a[c]);
          }
        }
        if (lane < 16){
          #pragma unroll
          for (int c = 0; c < 16; ++c)
            if (c <= r) Kl[rb + c] = a[c];
        }
      }
      __syncthreads();
      int t0p = j0 + 16;
      if (t0p < NP){
        // panel solve: rows below diag block
        if (tid < NP - t0p){
          int i = t0p + tid;
          int rb = IDX(i, j0);
          float a[16];
          #pragma unroll
          for (int qq = 0; qq < 4; ++qq){
            float4 v = *reinterpret_cast<const float4*>(&Kl[rb + 4*qq]);
            a[4*qq+0]=v.x; a[4*qq+1]=v.y; a[4*qq+2]=v.z; a[4*qq+3]=v.w;
          }
          #pragma unroll
          for (int c = 0; c < 16; ++c){
            float v = a[c];
            int cb = IDX(j0+c, j0);
            #pragma unroll
            for (int k = 0; k < 16; ++k){ if (k < c) v -= a[k]*Kl[cb + k]; }
            a[c] = clampf(v * invd[j0+c], 4.0f);   // |L~| <= 1 exact; clamp junk
          }
          #pragma unroll
          for (int qq = 0; qq < 4; ++qq){
            float4 v; v.x=a[4*qq]; v.y=a[4*qq+1]; v.z=a[4*qq+2]; v.w=a[4*qq+3];
            *reinterpret_cast<float4*>(&Kl[rb + 4*qq]) = v;
          }
        }
        __syncthreads();
        // trailing update A22 -= L21 L21^T
        int nt = NP - t0p;
        int ntr = nt >> 3;
        int offt = ntr*(ntr-1)/2;
        for (int tt = tid; tt < offt; tt += BLOCK){
          int r = (int)((sqrtf(8.0f*(float)tt + 1.0f) + 1.0f)*0.5f);
          while (r*(r-1)/2 > tt) --r;
          while ((r+1)*r/2 <= tt) ++r;
          int c = tt - r*(r-1)/2;
          int ri = t0p + r*8, rj = t0p + c*8;
          int ib[8], jb[8];
          #pragma unroll
          for (int q = 0; q < 8; ++q){ ib[q] = IDX(ri+q, j0); jb[q] = IDX(rj+q, j0); }
          float acc[64];
          #pragma unroll
          for (int q = 0; q < 64; ++q) acc[q] = 0.0f;
          #pragma unroll
          for (int ks = 0; ks < 4; ++ks){
            float4 Li[8], Lc[8];
            #pragma unroll
            for (int q = 0; q < 8; ++q) Li[q] = *reinterpret_cast<const float4*>(&Kl[ib[q] + 4*ks]);
            #pragma unroll
            for (int q = 0; q < 8; ++q) Lc[q] = *reinterpret_cast<const float4*>(&Kl[jb[q] + 4*ks]);
            #pragma unroll
            for (int rr = 0; rr < 8; ++rr){
              #pragma unroll
              for (int cc = 0; cc < 8; ++cc){
                float v = acc[rr*8+cc];
                v = fmaf(Li[rr].x, Lc[cc].x, v);
                v = fmaf(Li[rr].y, Lc[cc].y, v);
                v = fmaf(Li[rr].z, Lc[cc].z, v);
                v = fmaf(Li[rr].w, Lc[cc].w, v);
                acc[rr*8+cc] = v;
              }
            }
          }
          #pragma unroll
          for (int rr = 0; rr < 8; ++rr){
            int rb2 = IDX(ri+rr, rj);
            float4 v0 = *reinterpret_cast<const float4*>(&Kl[rb2]);
            float4 v1 = *reinterpret_cast<const float4*>(&Kl[rb2+4]);
            v0.x -= acc[rr*8+0]; v0.y -= acc[rr*8+1]; v0.z -= acc[rr*8+2]; v0.w -= acc[rr*8+3];
            v1.x -= acc[rr*8+4]; v1.y -= acc[rr*8+5]; v1.z -= acc[rr*8+6]; v1.w -= acc[rr*8+7];
            *reinterpret_cast<float4*>(&Kl[rb2])   = v0;
            *reinterpret_cast<float4*>(&Kl[rb2+4]) = v1;
          }
        }
        int nde = ntr*36;
        for (int e = tid; e < nde; e += BLOCK){
          int dt = e/36, e36 = e - dt*36;
          int rr = (int)((sqrtf(8.0f*(float)e36 + 1.0f) - 1.0f)*0.5f);
          while (rr*(rr+1)/2 > e36) --rr;
          while ((rr+1)*(rr+2)/2 <= e36) ++rr;
          int cc = e36 - rr*(rr+1)/2;
          int i  = t0p + dt*8 + rr;
          int jc = t0p + dt*8 + cc;
          int ri2 = IDX(i, j0), rj2 = IDX(jc, j0);
          float acc = 0.0f;
          #pragma unroll
          for (int ks = 0; ks < 4; ++ks){
            float4 av = *reinterpret_cast<const float4*>(&Kl[ri2 + 4*ks]);
            float4 bv = *reinterpret_cast<const float4*>(&Kl[rj2 + 4*ks]);
            acc = fmaf(av.x, bv.x, acc); acc = fmaf(av.y, bv.y, acc);
            acc = fmaf(av.z, bv.z, acc); acc = fmaf(av.w, bv.w, acc);
          }
          Kl[IDX(i, jc)] -= acc;
        }
      }
      __syncthreads();
    }

    // ---- G: forward solve L y = rhs~ (in yv) ----
    for (int pan = 0; pan < 16; ++pan){
      int j0 = pan*16;
      if (tid < 64){
        int r = lane & 15;
        int rb = IDX(j0 + r, j0);
        float l[16];
        #pragma unroll
        for (int qq = 0; qq < 4; ++qq){
          float4 v = *reinterpret_cast<const float4*>(&Kl[rb + 4*qq]);
          l[4*qq+0]=v.x; l[4*qq+1]=v.y; l[4*qq+2]=v.z; l[4*qq+3]=v.w;
        }
        float y   = yv[j0 + r];
        float miv = invd[j0 + r];
        #pragma unroll
        for (int j = 0; j < 16; ++j){
          float t = __shfl(y, j) * __shfl(miv, j);   // final y_j
          if (r == j) y = t;
          else if (r > j) y = fmaf(-l[j], t, y);
        }
        if (lane < 16) yv[j0 + r] = y;
      }
      __syncthreads();
      int t0p = j0 + 16;
      if (t0p < NP && tid < NP - t0p){
        int i = t0p + tid;
        int rb = IDX(i, j0);
        float acc = yv[i];
        #pragma unroll
        for (int k = 0; k < 16; ++k) acc -= Kl[rb + k]*yv[j0+k];
        yv[i] = acc;
      }
      __syncthreads();
    }
    // ---- H: back solve L^T dz~ = y (in yv) ----
    for (int pan = 15; pan >= 0; --pan){
      int j0 = pan*16;
      if (tid < 64){
        int r = lane & 15;
        float col[16];
        #pragma unroll
        for (int j = 0; j < 16; ++j) col[j] = Kl[IDX(j0 + j, j0) + r];  // L[j0+j][j0+r]
        float y   = yv[j0 + r];
        float miv = invd[j0 + r];
        #pragma unroll
        for (int j = 15; j >= 0; --j){
          float t = __shfl(y, j) * __shfl(miv, j);   // dz~_j
          if (r == j) y = t;
          else if (r < j) y = fmaf(-col[j], t, y);
        }
        if (lane < 16) yv[j0 + r] = y;
      }
      __syncthreads();
      if (j0 > 0 && tid < j0){
        int i = tid;
        float acc = yv[i];
        #pragma unroll
        for (int k = 0; k < 16; ++k) acc -= Kl[IDX(j0+k, i)]*yv[j0+k];
        yv[i] = acc;
      }
      __syncthreads();
    }
    // ---- unscale: dz = S dz~ ----
    if (tid < NP) yv[tid] = clampf(yv[tid]*dscv[tid], 1e30f);
    __syncthreads();

    // ---- I: ds = -r2 - dz @ G^T (wave-per-row) ----
    {
      int kb = wv*32, ke = min(kb + 32, NI);
      float z0l = yv[lane], z1l = yv[lane+64], z2l = yv[lane+128];
      float z3l = (lane < 63) ? yv[lane+192] : 0.0f;
      for (int k = kb; k < ke; k += 2){
        const float* g0 = G + k*NH;
        const float* g1 = g0 + NH;
        float a3 = (lane < 63) ? g0[lane+192] : 0.0f;
        float b3 = (lane < 63) ? g1[lane+192] : 0.0f;
        float v0 = g0[lane]*z0l + g0[lane+64]*z1l + g0[lane+128]*z2l + a3*z3l;
        float v1 = g1[lane]*z0l + g1[lane+64]*z1l + g1[lane+128]*z2l + b3*z3l;
        #pragma unroll
        for (int m = 32; m >= 1; m >>= 1){ v0 += __shfl_xor(v0, m, 64); v1 += __shfl_xor(v1, m, 64); }
        if (lane == 0){
          dsv[k]   = clampf(-r2[k]   - v0, 1e30f);
          dsv[k+1] = clampf(-r2[k+1] - v1, 1e30f);
        }
      }
    }
    __syncthreads();
    // ---- J: dlam, alpha ----
    float loc = 1e10f;
    if (tid < NI){
      float dsk = dsv[tid];
      float skg = fmaxf(sv[tid], 1e-30f);
      float dlk = clampf((-r3[tid] - lv[tid]*dsk)/skg, 1e30f);
      dlv[tid] = dlk;
      if (dsk < 0.0f) loc = fminf(loc, -sv[tid]/dsk);
      if (dlk < 0.0f) loc = fminf(loc, -lv[tid]/dlk);
    }
    #pragma unroll
    for (int m = 32; m >= 1; m >>= 1) loc = fminf(loc, __shfl_xor(loc, m, 64));
    if (lane == 0) misc[wv] = loc;
    __syncthreads();
    if (tid == 0){
      float mn = 1e10f;
      #pragma unroll
      for (int q = 0; q < 8; ++q) mn = fminf(mn, misc[q]);
      misc[16] = fminf(1.0f, 0.99f*mn);
    }
    __syncthreads();
    {
      float alpha = misc[16];
      if (tid < NP) zv[tid] += alpha*yv[tid];
      if (tid < NI){
        sv[tid] += alpha*dsv[tid];
        lv[tid] += alpha*dlv[tid];
      }
    }
    __syncthreads();
  }

  if (tid < NFEAT) out[b*NFEAT + tid] = zv[tid];
}

extern "C" void kernel_launch(void* const* d_in, const int* in_sizes, int n_in,
                              void* d_out, int out_size, void* d_ws, size_t ws_size,
                              hipStream_t stream)
{
  const float* x    = (const float*)d_in[0];
  const float* W    = (const float*)d_in[1];
  const float* bias = (const float*)d_in[2];
  const float* L    = (const float*)d_in[3];
  const float* G    = (const float*)d_in[4];
  const float* z0   = (const float*)d_in[5];
  const float* s0   = (const float*)d_in[6];
  float* out = (float*)d_out;

  float* ws = (float*)d_ws;
  float* Qg = ws;               // 65536 floats
  float* Pg = Qg + 65536;       // 32768
  float* Hg = Pg + 32768;       // 256

  hipLaunchKernelGGL(k_setupQ, dim3(NP),     dim3(NP), 0, stream, L, Qg);
  hipLaunchKernelGGL(k_setupP, dim3(NBATCH), dim3(NP), 0, stream, x, W, bias, Pg);
  hipLaunchKernelGGL(k_setupH, dim3(1),      dim3(NP), 0, stream, G, z0, s0, Hg);

  hipFuncSetAttribute(reinterpret_cast<const void*>(qp_kernel),
                      hipFuncAttributeMaxDynamicSharedMemorySize, SMEM_BYTES);
  hipLaunchKernelGGL(qp_kernel, dim3(NBATCH), dim3(BLOCK), SMEM_BYTES, stream,
                     Qg, G, Pg, Hg, out);
}

// Round 4
// 37702.200 us; speedup vs baseline: 1.0046x; 1.0046x over previous
//
#include <hip/hip_runtime.h>
#include <math.h>

#define NFEAT 128
#define NH 255
#define NP 256
#define NI 254
#define NBATCH 128
#define EPSQ 1e-4f
#define NITER 20
#define SIGMA 0.1f
#define BLOCK 512
#define KBCH 8
#define KLSIZE 33280   /* packed lower triangle, rows padded to 4-float alignment */
#define SMEM_FLOATS (KLSIZE + KBCH*256 + 15*256 + 64)
#define SMEM_BYTES (SMEM_FLOATS*4)

// padded packed lower-triangle index: row i starts at 4*(a+1)*(2a+b), a=i>>2, b=i&3
__device__ __forceinline__ int IDX(int i, int j){
  int a = i >> 2, bb = i & 3;
  return 4*(a+1)*(2*a + bb) + j;
}
__device__ __forceinline__ float clampf(float x, float m){
  // also scrubs NaN -> -m (fmaxf/fminf return the non-NaN operand)
  return fminf(fmaxf(x, -m), m);
}

// ---------------- setup kernels (read L/W directly; minimal workspace) ----------------
__global__ void k_setupQ(const float* __restrict__ L, float* __restrict__ Q){
  int i = blockIdx.x, j = threadIdx.x;
  float acc;
  if (i < NH && j < NH){
    int kmax = (i < j) ? i : j;
    acc = 0.0f;
    for (int k = 0; k <= kmax; ++k) acc = fmaf(L[i*NH + k], L[j*NH + k], acc);
    if (i == j) acc += EPSQ;
  } else {
    acc = (i == j) ? 1.0f : 0.0f;   // padded row/col 255 = e255
  }
  Q[i*NP + j] = acc;
}
__global__ void k_setupP(const float* __restrict__ x, const float* __restrict__ W,
                         const float* __restrict__ bias, float* __restrict__ P){
  int b = blockIdx.x, j = threadIdx.x;
  float acc = 0.0f;
  if (j < NH){
    acc = bias[j];
    for (int f = 0; f < NFEAT; ++f) acc = fmaf(x[b*NFEAT + f], W[j*NFEAT + f], acc);
  }
  P[b*NP + j] = acc;
}
__global__ void k_setupH(const float* __restrict__ G, const float* __restrict__ z0,
                         const float* __restrict__ s0, float* __restrict__ H){
  int k = threadIdx.x;
  float acc = 0.0f;
  if (k < NI){
    acc = s0[k];
    for (int i = 0; i < NH; ++i) acc = fmaf(G[k*NH + i], z0[i], acc);
  }
  H[k] = acc;
}

// ---------------- main QP kernel: one block per batch row ----------------
// __launch_bounds__(512, 2): 8 waves/block = 2 waves/SIMD at 1 block/CU (LDS-capped),
// so allow up to 256 VGPR/thread -> hot-loop accumulators stay in registers (no spill).
__global__ void __launch_bounds__(BLOCK, 2) qp_kernel(
    const float* __restrict__ Qg, const float* __restrict__ G,
    const float* __restrict__ Pg, const float* __restrict__ Hg,
    float* __restrict__ out)
{
  extern __shared__ float sm[];
  float* Kl   = sm;                 // 33280
  float* gb   = Kl + KLSIZE;        // KBCH*256
  float* zv   = gb + KBCH*256;
  float* sv   = zv + NP;
  float* lv   = sv + NP;
  float* psh  = lv + NP;
  float* hsh  = psh + NP;
  float* r1   = hsh + NP;
  float* r2   = r1 + NP;
  float* r3   = r2 + NP;
  float* dd   = r3 + NP;
  float* wwv  = dd + NP;
  float* dsv  = wwv + NP;
  float* dlv  = dsv + NP;
  float* yv   = dlv + NP;
  float* invd = yv + NP;
  float* dscv = invd + NP;
  float* misc = dscv + NP;          // 64

  const int tid  = threadIdx.x;
  const int lane = tid & 63;
  const int wv   = tid >> 6;
  const int b    = blockIdx.x;

  // ---- zero ALL of LDS: padding slots of the packed triangle stay 0 forever,
  // so every float4 over-read is benign by construction ----
  for (int i = tid; i < SMEM_FLOATS; i += BLOCK) sm[i] = 0.0f;
  __syncthreads();

  // ---- static mappings ----
  // off-diagonal 8x8 K tiles: tid<496 -> (tr,tc), tr in 1..31, tc<tr
  int ktr = 0, ktc = 0;
  if (tid < 496){
    int t = tid;
    int r = (int)((sqrtf(8.0f*(float)t + 1.0f) + 1.0f)*0.5f);
    while (r*(r-1)/2 > t) --r;
    while ((r+1)*r/2 <= t) ++r;
    ktr = r; ktc = t - r*(r-1)/2;
  }
  const int i0 = ktr*8, j0k = ktc*8;

  // diagonal-tile elements (32 tiles x 36 elems = 1152), up to 3 per thread
  int dI[3], dJ[3];
  #pragma unroll
  for (int q = 0; q < 3; ++q){
    int e = tid + 512*q;
    if (e < 1152){
      int dt = e/36, e36 = e - dt*36;
      int r = (int)((sqrtf(8.0f*(float)e36 + 1.0f) - 1.0f)*0.5f);
      while (r*(r+1)/2 > e36) --r;
      while ((r+1)*(r+2)/2 <= e36) ++r;
      int c = e36 - r*(r+1)/2;
      dI[q] = dt*8 + r; dJ[q] = dt*8 + c;
    } else { dI[q] = -1; dJ[q] = 0; }
  }

  // ---- init state ----
  for (int i = tid; i < NP; i += BLOCK){
    zv[i] = 0.0f;
    sv[i] = 1.0f;
    lv[i] = (i < NI) ? 1.0f : 0.0f;
    psh[i] = Pg[b*NP + i];
    hsh[i] = Hg[i];
  }
  __syncthreads();

  for (int it = 0; it < NITER; ++it){
    // ---- A1: r1 = Q z (wave-per-row, 2 rows at a time) ----
    {
      int ib0 = wv*32;
      float z0l = zv[lane], z1l = zv[lane+64], z2l = zv[lane+128], z3l = zv[lane+192];
      for (int i = ib0; i < ib0 + 32; i += 2){
        const float* q0 = Qg + i*NP;
        const float* q1 = q0 + NP;
        float v0 = q0[lane]*z0l + q0[lane+64]*z1l + q0[lane+128]*z2l + q0[lane+192]*z3l;
        float v1 = q1[lane]*z0l + q1[lane+64]*z1l + q1[lane+128]*z2l + q1[lane+192]*z3l;
        #pragma unroll
        for (int m = 32; m >= 1; m >>= 1){ v0 += __shfl_xor(v0, m, 64); v1 += __shfl_xor(v1, m, 64); }
        if (lane == 0){ r1[i] = v0; r1[i+1] = v1; }
      }
    }
    // ---- A2: G^T lam partials ----
    {
      int i  = tid & 255;
      int k0 = (tid < 256) ? 0 : 127;
      int k1 = (tid < 256) ? 127 : NI;
      float acc = 0.0f;
      if (i < NH){
        const float* gp = G + k0*NH + i;
        #pragma unroll 4
        for (int k = k0; k < k1; ++k){ acc = fmaf(*gp, lv[k], acc); gp += NH; }
      }
      if (tid < 256) dsv[i] = acc; else dlv[i] = acc;
    }
    __syncthreads();
    // ---- A3: combine r1 ----
    if (tid < NP) r1[tid] = r1[tid] + psh[tid] + dsv[tid] + dlv[tid];
    // ---- B: r2 = G z + s - h (wave-per-row) ----
    {
      int kb = wv*32, ke = min(kb + 32, NI);
      float z0l = zv[lane], z1l = zv[lane+64], z2l = zv[lane+128];
      float z3l = (lane < 63) ? zv[lane+192] : 0.0f;
      for (int k = kb; k < ke; k += 2){
        const float* g0 = G + k*NH;
        const float* g1 = g0 + NH;
        float a3 = (lane < 63) ? g0[lane+192] : 0.0f;
        float b3 = (lane < 63) ? g1[lane+192] : 0.0f;
        float v0 = g0[lane]*z0l + g0[lane+64]*z1l + g0[lane+128]*z2l + a3*z3l;
        float v1 = g1[lane]*z0l + g1[lane+64]*z1l + g1[lane+128]*z2l + b3*z3l;
        #pragma unroll
        for (int m = 32; m >= 1; m >>= 1){ v0 += __shfl_xor(v0, m, 64); v1 += __shfl_xor(v1, m, 64); }
        if (lane == 0){
          r2[k]   = v0 + sv[k]   - hsh[k];
          r2[k+1] = v1 + sv[k+1] - hsh[k+1];
        }
      }
    }
    __syncthreads();
    // ---- C: mu, r3, d, w ----
    {
      float sl = (tid < NI) ? sv[tid]*lv[tid] : 0.0f;
      #pragma unroll
      for (int m = 32; m >= 1; m >>= 1) sl += __shfl_xor(sl, m, 64);
      if (lane == 0) misc[wv] = sl;
    }
    __syncthreads();
    if (tid == 0){
      float t = 0.0f;
      #pragma unroll
      for (int q = 0; q < 8; ++q) t += misc[q];
      misc[17] = SIGMA * (t * (1.0f/(float)NI));
    }
    __syncthreads();
    if (tid < NI){
      float sk = sv[tid], lk = lv[tid];
      float skg = fmaxf(sk, 1e-30f);                 // FTZ guard
      float r3k = sk*lk - misc[17];
      r3[tid] = r3k;
      dd[tid] = fminf(lk/skg, 1e24f);                // keep K build finite
      wwv[tid] = clampf((lk*r2[tid] - r3k)/skg, 1e30f);
    }
    __syncthreads();
    // ---- D0: K diagonal -> Jacobi equilibration scale dscv ----
    {
      int i  = tid & 255;
      int k0 = (tid < 256) ? 0 : 127;
      int k1 = (tid < 256) ? 127 : NI;
      float acc = 0.0f;
      if (i < NH){
        const float* gp = G + k0*NH + i;
        #pragma unroll 4
        for (int k = k0; k < k1; ++k){ float g = *gp; acc = fmaf(dd[k]*g, g, acc); gp += NH; }
      }
      if (tid < 256) dsv[i] = acc; else dlv[i] = acc;
    }
    __syncthreads();
    if (tid < NP){
      float diag = Qg[tid*NP + tid] + dsv[tid] + dlv[tid];
      dscv[tid] = rsqrtf(fmaxf(diag, 1e-12f));
    }
    __syncthreads();
    // ---- D: rhs = -(r1 + w @ G); scaled rhs~ = dsc * rhs -> yv ----
    {
      int i  = tid & 255;
      int k0 = (tid < 256) ? 0 : 127;
      int k1 = (tid < 256) ? 127 : NI;
      float acc = 0.0f;
      if (i < NH){
        const float* gp = G + k0*NH + i;
        #pragma unroll 4
        for (int k = k0; k < k1; ++k){ acc = fmaf(*gp, wwv[k], acc); gp += NH; }
      }
      if (tid < 256) dsv[i] = acc; else dlv[i] = acc;
    }
    __syncthreads();
    if (tid < NP) yv[tid] = -(r1[tid] + dsv[tid] + dlv[tid]) * dscv[tid];

    // ---- E: K~ = S(Q + G^T D G)S packed lower triangle in LDS ----
    // Scaled SPD with unit diagonal => all entries in [-1,1], |L~| <= 1: no overflow.
    float accT[64];
    if (tid < 496){
      #pragma unroll
      for (int r = 0; r < 8; ++r){
        float4 qa = *reinterpret_cast<const float4*>(&Qg[(i0+r)*NP + j0k]);
        float4 qb = *reinterpret_cast<const float4*>(&Qg[(i0+r)*NP + j0k + 4]);
        accT[r*8+0]=qa.x; accT[r*8+1]=qa.y; accT[r*8+2]=qa.z; accT[r*8+3]=qa.w;
        accT[r*8+4]=qb.x; accT[r*8+5]=qb.y; accT[r*8+6]=qb.z; accT[r*8+7]=qb.w;
      }
    }
    float accD[3];
    #pragma unroll
    for (int q = 0; q < 3; ++q) accD[q] = (dI[q] >= 0) ? Qg[dI[q]*NP + dJ[q]] : 0.0f;

    for (int c0 = 0; c0 < NP; c0 += KBCH){
      __syncthreads();
      { // stage sqrt(d[k]) * G[k][:] rows c0..c0+7 (zero-padded)
        int base = tid*4;
        int kk = base >> 8;
        int j  = base & 255;
        int krow = c0 + kk;
        float4 v; v.x = v.y = v.z = v.w = 0.0f;
        if (krow < NI){
          float sd = sqrtf(dd[krow]);
          const float* gr = G + krow*NH + j;
          v.x = gr[0]*sd;
          v.y = gr[1]*sd;
          v.z = gr[2]*sd;
          v.w = (j + 3 < NH) ? gr[3]*sd : 0.0f;
        }
        *reinterpret_cast<float4*>(&gb[base]) = v;
      }
      __syncthreads();
      #pragma unroll
      for (int kk = 0; kk < KBCH; ++kk){
        const float* gr = gb + kk*256;
        #pragma unroll
        for (int q = 0; q < 3; ++q)
          if (dI[q] >= 0) accD[q] = fmaf(gr[dI[q]], gr[dJ[q]], accD[q]);
        if (tid < 496){
          float4 a0 = *reinterpret_cast<const float4*>(&gr[i0]);
          float4 a1 = *reinterpret_cast<const float4*>(&gr[i0+4]);
          float4 b0 = *reinterpret_cast<const float4*>(&gr[j0k]);
          float4 b1 = *reinterpret_cast<const float4*>(&gr[j0k+4]);
          float gi[8] = {a0.x,a0.y,a0.z,a0.w,a1.x,a1.y,a1.z,a1.w};
          float gj[8] = {b0.x,b0.y,b0.z,b0.w,b1.x,b1.y,b1.z,b1.w};
          #pragma unroll
          for (int r = 0; r < 8; ++r){
            #pragma unroll
            for (int c = 0; c < 8; ++c) accT[r*8+c] = fmaf(gi[r], gj[c], accT[r*8+c]);
          }
        }
      }
    }
    __syncthreads();
    if (tid < 496){
      float sj[8];
      #pragma unroll
      for (int c = 0; c < 8; ++c) sj[c] = dscv[j0k + c];
      #pragma unroll
      for (int r = 0; r < 8; ++r){
        float sr = dscv[i0 + r];
        int rb = IDX(i0+r, j0k);
        float4 v0, v1;
        v0.x=accT[r*8+0]*sr*sj[0]; v0.y=accT[r*8+1]*sr*sj[1];
        v0.z=accT[r*8+2]*sr*sj[2]; v0.w=accT[r*8+3]*sr*sj[3];
        v1.x=accT[r*8+4]*sr*sj[4]; v1.y=accT[r*8+5]*sr*sj[5];
        v1.z=accT[r*8+6]*sr*sj[6]; v1.w=accT[r*8+7]*sr*sj[7];
        *reinterpret_cast<float4*>(&Kl[rb])   = v0;
        *reinterpret_cast<float4*>(&Kl[rb+4]) = v1;
      }
    }
    #pragma unroll
    for (int q = 0; q < 3; ++q)
      if (dI[q] >= 0) Kl[IDX(dI[q], dJ[q])] = accD[q]*dscv[dI[q]]*dscv[dJ[q]];
    __syncthreads();

    // ---- F: blocked Cholesky (NB=16) on K~ (row 255 = e255 stays inert) ----
    for (int pan = 0; pan < 16; ++pan){
      int j0 = pan*16;
      // 16x16 diag factor: single wave, all-register, shuffle-based.
      if (tid < 64){
        int r = lane & 15;
        int rb = IDX(j0 + r, j0);
        float a[16];
        #pragma unroll
        for (int qq = 0; qq < 4; ++qq){
          float4 v = *reinterpret_cast<const float4*>(&Kl[rb + 4*qq]);
          a[4*qq+0]=v.x; a[4*qq+1]=v.y; a[4*qq+2]=v.z; a[4*qq+3]=v.w;
        }
        #pragma unroll
        for (int j = 0; j < 16; ++j){
          float dj = __shfl(a[j], j);              // updated A[j][j] from lane j
          dj = (dj > 1e-8f) ? dj : 1e-8f;          // relative pivot floor (scrubs NaN)
          float piv = sqrtf(dj);
          float inv = 1.0f/piv;
          float lrj = clampf(a[j]*inv, 4.0f);      // |L~| <= 1 in exact arithmetic
          a[j] = (r == j) ? piv : lrj;
          if (lane == j) invd[j0+j] = inv;
          #pragma unroll
          for (int c = j+1; c < 16; ++c){
            float lcj = __shfl(a[j], c);           // L[c][j] from lane c
            a[c] = fmaf(-a[j], lcj, a[c]);
          }
        }
        if (lane < 16){
          #pragma unroll
          for (int c = 0; c < 16; ++c)
            if (c <= r) Kl[rb + c] = a[c];
        }
      }
      __syncthreads();
      int t0p = j0 + 16;
      if (t0p < NP){
        // panel solve: rows below diag block
        if (tid < NP - t0p){
          int i = t0p + tid;
          int rb = IDX(i, j0);
          float a[16];
          #pragma unroll
          for (int qq = 0; qq < 4; ++qq){
            float4 v = *reinterpret_cast<const float4*>(&Kl[rb + 4*qq]);
            a[4*qq+0]=v.x; a[4*qq+1]=v.y; a[4*qq+2]=v.z; a[4*qq+3]=v.w;
          }
          #pragma unroll
          for (int c = 0; c < 16; ++c){
            float v = a[c];
            int cb = IDX(j0+c, j0);
            #pragma unroll
            for (int k = 0; k < 16; ++k){ if (k < c) v -= a[k]*Kl[cb + k]; }
            a[c] = clampf(v * invd[j0+c], 4.0f);   // |L~| <= 1 exact; clamp junk
          }
          #pragma unroll
          for (int qq = 0; qq < 4; ++qq){
            float4 v; v.x=a[4*qq]; v.y=a[4*qq+1]; v.z=a[4*qq+2]; v.w=a[4*qq+3];
            *reinterpret_cast<float4*>(&Kl[rb + 4*qq]) = v;
          }
        }
        __syncthreads();
        // trailing update A22 -= L21 L21^T
        int nt = NP - t0p;
        int ntr = nt >> 3;
        int offt = ntr*(ntr-1)/2;
        for (int tt = tid; tt < offt; tt += BLOCK){
          int r = (int)((sqrtf(8.0f*(float)tt + 1.0f) + 1.0f)*0.5f);
          while (r*(r-1)/2 > tt) --r;
          while ((r+1)*r/2 <= tt) ++r;
          int c = tt - r*(r-1)/2;
          int ri = t0p + r*8, rj = t0p + c*8;
          int ib[8], jb[8];
          #pragma unroll
          for (int q = 0; q < 8; ++q){ ib[q] = IDX(ri+q, j0); jb[q] = IDX(rj+q, j0); }
          float acc[64];
          #pragma unroll
          for (int q = 0; q < 64; ++q) acc[q] = 0.0f;
          #pragma unroll
          for (int ks = 0; ks < 4; ++ks){
            float4 Li[8], Lc[8];
            #pragma unroll
            for (int q = 0; q < 8; ++q) Li[q] = *reinterpret_cast<const float4*>(&Kl[ib[q] + 4*ks]);
            #pragma unroll
            for (int q = 0; q < 8; ++q) Lc[q] = *reinterpret_cast<const float4*>(&Kl[jb[q] + 4*ks]);
            #pragma unroll
            for (int rr = 0; rr < 8; ++rr){
              #pragma unroll
              for (int cc = 0; cc < 8; ++cc){
                float v = acc[rr*8+cc];
                v = fmaf(Li[rr].x, Lc[cc].x, v);
                v = fmaf(Li[rr].y, Lc[cc].y, v);
                v = fmaf(Li[rr].z, Lc[cc].z, v);
                v = fmaf(Li[rr].w, Lc[cc].w, v);
                acc[rr*8+cc] = v;
              }
            }
          }
          #pragma unroll
          for (int rr = 0; rr < 8; ++rr){
            int rb2 = IDX(ri+rr, rj);
            float4 v0 = *reinterpret_cast<const float4*>(&Kl[rb2]);
            float4 v1 = *reinterpret_cast<const float4*>(&Kl[rb2+4]);
            v0.x -= acc[rr*8+0]; v0.y -= acc[rr*8+1]; v0.z -= acc[rr*8+2]; v0.w -= acc[rr*8+3];
            v1.x -= acc[rr*8+4]; v1.y -= acc[rr*8+5]; v1.z -= acc[rr*8+6]; v1.w -= acc[rr*8+7];
            *reinterpret_cast<float4*>(&Kl[rb2])   = v0;
            *reinterpret_cast<float4*>(&Kl[rb2+4]) = v1;
          }
        }
        int nde = ntr*36;
        for (int e = tid; e < nde; e += BLOCK){
          int dt = e/36, e36 = e - dt*36;
          int rr = (int)((sqrtf(8.0f*(float)e36 + 1.0f) - 1.0f)*0.5f);
          while (rr*(rr+1)/2 > e36) --rr;
          while ((rr+1)*(rr+2)/2 <= e36) ++rr;
          int cc = e36 - rr*(rr+1)/2;
          int i  = t0p + dt*8 + rr;
          int jc = t0p + dt*8 + cc;
          int ri2 = IDX(i, j0), rj2 = IDX(jc, j0);
          float acc = 0.0f;
          #pragma unroll
          for (int ks = 0; ks < 4; ++ks){
            float4 av = *reinterpret_cast<const float4*>(&Kl[ri2 + 4*ks]);
            float4 bv = *reinterpret_cast<const float4*>(&Kl[rj2 + 4*ks]);
            acc = fmaf(av.x, bv.x, acc); acc = fmaf(av.y, bv.y, acc);
            acc = fmaf(av.z, bv.z, acc); acc = fmaf(av.w, bv.w, acc);
          }
          Kl[IDX(i, jc)] -= acc;
        }
      }
      __syncthreads();
    }

    // ---- G: forward solve L y = rhs~ (in yv) ----
    for (int pan = 0; pan < 16; ++pan){
      int j0 = pan*16;
      if (tid < 64){
        int r = lane & 15;
        int rb = IDX(j0 + r, j0);
        float l[16];
        #pragma unroll
        for (int qq = 0; qq < 4; ++qq){
          float4 v = *reinterpret_cast<const float4*>(&Kl[rb + 4*qq]);
          l[4*qq+0]=v.x; l[4*qq+1]=v.y; l[4*qq+2]=v.z; l[4*qq+3]=v.w;
        }
        float y   = yv[j0 + r];
        float miv = invd[j0 + r];
        #pragma unroll
        for (int j = 0; j < 16; ++j){
          float t = __shfl(y, j) * __shfl(miv, j);   // final y_j
          if (r == j) y = t;
          else if (r > j) y = fmaf(-l[j], t, y);
        }
        if (lane < 16) yv[j0 + r] = y;
      }
      __syncthreads();
      int t0p = j0 + 16;
      if (t0p < NP && tid < NP - t0p){
        int i = t0p + tid;
        int rb = IDX(i, j0);
        float acc = yv[i];
        #pragma unroll
        for (int k = 0; k < 16; ++k) acc -= Kl[rb + k]*yv[j0+k];
        yv[i] = acc;
      }
      __syncthreads();
    }
    // ---- H: back solve L^T dz~ = y (in yv) ----
    for (int pan = 15; pan >= 0; --pan){
      int j0 = pan*16;
      if (tid < 64){
        int r = lane & 15;
        float col[16];
        #pragma unroll
        for (int j = 0; j < 16; ++j) col[j] = Kl[IDX(j0 + j, j0) + r];  // L[j0+j][j0+r]
        float y   = yv[j0 + r];
        float miv = invd[j0 + r];
        #pragma unroll
        for (int j = 15; j >= 0; --j){
          float t = __shfl(y, j) * __shfl(miv, j);   // dz~_j
          if (r == j) y = t;
          else if (r < j) y = fmaf(-col[j], t, y);
        }
        if (lane < 16) yv[j0 + r] = y;
      }
      __syncthreads();
      if (j0 > 0 && tid < j0){
        int i = tid;
        float acc = yv[i];
        #pragma unroll
        for (int k = 0; k < 16; ++k) acc -= Kl[IDX(j0+k, i)]*yv[j0+k];
        yv[i] = acc;
      }
      __syncthreads();
    }
    // ---- unscale: dz = S dz~ ----
    if (tid < NP) yv[tid] = clampf(yv[tid]*dscv[tid], 1e30f);
    __syncthreads();

    // ---- I: ds = -r2 - dz @ G^T (wave-per-row) ----
    {
      int kb = wv*32, ke = min(kb + 32, NI);
      float z0l = yv[lane], z1l = yv[lane+64], z2l = yv[lane+128];
      float z3l = (lane < 63) ? yv[lane+192] : 0.0f;
      for (int k = kb; k < ke; k += 2){
        const float* g0 = G + k*NH;
        const float* g1 = g0 + NH;
        float a3 = (lane < 63) ? g0[lane+192] : 0.0f;
        float b3 = (lane < 63) ? g1[lane+192] : 0.0f;
        float v0 = g0[lane]*z0l + g0[lane+64]*z1l + g0[lane+128]*z2l + a3*z3l;
        float v1 = g1[lane]*z0l + g1[lane+64]*z1l + g1[lane+128]*z2l + b3*z3l;
        #pragma unroll
        for (int m = 32; m >= 1; m >>= 1){ v0 += __shfl_xor(v0, m, 64); v1 += __shfl_xor(v1, m, 64); }
        if (lane == 0){
          dsv[k]   = clampf(-r2[k]   - v0, 1e30f);
          dsv[k+1] = clampf(-r2[k+1] - v1, 1e30f);
        }
      }
    }
    __syncthreads();
    // ---- J: dlam, alpha ----
    float loc = 1e10f;
    if (tid < NI){
      float dsk = dsv[tid];
      float skg = fmaxf(sv[tid], 1e-30f);
      float dlk = clampf((-r3[tid] - lv[tid]*dsk)/skg, 1e30f);
      dlv[tid] = dlk;
      if (dsk < 0.0f) loc = fminf(loc, -sv[tid]/dsk);
      if (dlk < 0.0f) loc = fminf(loc, -lv[tid]/dlk);
    }
    #pragma unroll
    for (int m = 32; m >= 1; m >>= 1) loc = fminf(loc, __shfl_xor(loc, m, 64));
    if (lane == 0) misc[wv] = loc;
    __syncthreads();
    if (tid == 0){
      float mn = 1e10f;
      #pragma unroll
      for (int q = 0; q < 8; ++q) mn = fminf(mn, misc[q]);
      misc[16] = fminf(1.0f, 0.99f*mn);
    }
    __syncthreads();
    {
      float alpha = misc[16];
      if (tid < NP) zv[tid] += alpha*yv[tid];
      if (tid < NI){
        sv[tid] += alpha*dsv[tid];
        lv[tid] += alpha*dlv[tid];
      }
    }
    __syncthreads();
  }

  if (tid < NFEAT) out[b*NFEAT + tid] = zv[tid];
}

extern "C" void kernel_launch(void* const* d_in, const int* in_sizes, int n_in,
                              void* d_out, int out_size, void* d_ws, size_t ws_size,
                              hipStream_t stream)
{
  const float* x    = (const float*)d_in[0];
  const float* W    = (const float*)d_in[1];
  const float* bias = (const float*)d_in[2];
  const float* L    = (const float*)d_in[3];
  const float* G    = (const float*)d_in[4];
  const float* z0   = (const float*)d_in[5];
  const float* s0   = (const float*)d_in[6];
  float* out = (float*)d_out;

  float* ws = (float*)d_ws;
  float* Qg = ws;               // 65536 floats
  float* Pg = Qg + 65536;       // 32768
  float* Hg = Pg + 32768;       // 256

  hipLaunchKernelGGL(k_setupQ, dim3(NP),     dim3(NP), 0, stream, L, Qg);
  hipLaunchKernelGGL(k_setupP, dim3(NBATCH), dim3(NP), 0, stream, x, W, bias, Pg);
  hipLaunchKernelGGL(k_setupH, dim3(1),      dim3(NP), 0, stream, G, z0, s0, Hg);

  hipFuncSetAttribute(reinterpret_cast<const void*>(qp_kernel),
                      hipFuncAttributeMaxDynamicSharedMemorySize, SMEM_BYTES);
  hipLaunchKernelGGL(qp_kernel, dim3(NBATCH), dim3(BLOCK), SMEM_BYTES, stream,
                     Qg, G, Pg, Hg, out);
}

// Round 5
// 36065.491 us; speedup vs baseline: 1.0502x; 1.0454x over previous
//
#include <hip/hip_runtime.h>
#include <math.h>

#define NFEAT 128
#define NH 255
#define NP 256
#define NI 254
#define NBATCH 128
#define EPSQ 1e-4f
#define NITER 20
#define SIGMA 0.1f
#define BLOCK 512
#define KBCH 8
#define KLSIZE 33280   /* packed lower triangle, rows padded to 4-float alignment */
#define SMEM_FLOATS (KLSIZE + KBCH*256 + 15*256 + 64)
#define SMEM_BYTES (SMEM_FLOATS*4)

// padded packed lower-triangle index: row i starts at 4*(a+1)*(2a+b), a=i>>2, b=i&3
__device__ __forceinline__ int IDX(int i, int j){
  int a = i >> 2, bb = i & 3;
  return 4*(a+1)*(2*a + bb) + j;
}
__device__ __forceinline__ float clampf(float x, float m){
  // also scrubs NaN -> -m (fmaxf/fminf return the non-NaN operand)
  return fminf(fmaxf(x, -m), m);
}

// ---------------- setup kernels (read L/W directly; minimal workspace) ----------------
__global__ void k_setupQ(const float* __restrict__ L, float* __restrict__ Q){
  int i = blockIdx.x, j = threadIdx.x;
  float acc;
  if (i < NH && j < NH){
    int kmax = (i < j) ? i : j;
    acc = 0.0f;
    for (int k = 0; k <= kmax; ++k) acc = fmaf(L[i*NH + k], L[j*NH + k], acc);
    if (i == j) acc += EPSQ;
  } else {
    acc = (i == j) ? 1.0f : 0.0f;   // padded row/col 255 = e255
  }
  Q[i*NP + j] = acc;
}
__global__ void k_setupP(const float* __restrict__ x, const float* __restrict__ W,
                         const float* __restrict__ bias, float* __restrict__ P){
  int b = blockIdx.x, j = threadIdx.x;
  float acc = 0.0f;
  if (j < NH){
    acc = bias[j];
    for (int f = 0; f < NFEAT; ++f) acc = fmaf(x[b*NFEAT + f], W[j*NFEAT + f], acc);
  }
  P[b*NP + j] = acc;
}
__global__ void k_setupH(const float* __restrict__ G, const float* __restrict__ z0,
                         const float* __restrict__ s0, float* __restrict__ H){
  int k = threadIdx.x;
  float acc = 0.0f;
  if (k < NI){
    acc = s0[k];
    for (int i = 0; i < NH; ++i) acc = fmaf(G[k*NH + i], z0[i], acc);
  }
  H[k] = acc;
}

// ---------------- main QP kernel: one block per batch row ----------------
// amdgpu_waves_per_eu(2): LDS (152KB) caps us at 1 block/CU = 8 waves = 2 waves/SIMD
// anyway; declaring min 2 waves/EU legalizes a 256-VGPR budget so the hot-loop
// accumulators (accT[64], acc[64]) live entirely in registers (round 4: 128-VGPR cap
// -> 10 GB of scratch spill traffic per dispatch, VALUBusy 2%).
__global__ void __launch_bounds__(BLOCK) __attribute__((amdgpu_waves_per_eu(2)))
qp_kernel(
    const float* __restrict__ Qg, const float* __restrict__ G,
    const float* __restrict__ Pg, const float* __restrict__ Hg,
    float* __restrict__ out)
{
  extern __shared__ float sm[];
  float* Kl   = sm;                 // 33280
  float* gb   = Kl + KLSIZE;        // KBCH*256
  float* zv   = gb + KBCH*256;
  float* sv   = zv + NP;
  float* lv   = sv + NP;
  float* psh  = lv + NP;
  float* hsh  = psh + NP;
  float* r1   = hsh + NP;
  float* r2   = r1 + NP;
  float* r3   = r2 + NP;
  float* dd   = r3 + NP;
  float* wwv  = dd + NP;
  float* dsv  = wwv + NP;
  float* dlv  = dsv + NP;
  float* yv   = dlv + NP;
  float* invd = yv + NP;
  float* dscv = invd + NP;
  float* misc = dscv + NP;          // 64

  const int tid  = threadIdx.x;
  const int lane = tid & 63;
  const int wv   = tid >> 6;
  const int b    = blockIdx.x;

  // ---- zero ALL of LDS: padding slots of the packed triangle stay 0 forever,
  // so every float4 over-read is benign by construction ----
  for (int i = tid; i < SMEM_FLOATS; i += BLOCK) sm[i] = 0.0f;
  __syncthreads();

  // ---- static mappings ----
  // off-diagonal 8x8 K tiles: tid<496 -> (tr,tc), tr in 1..31, tc<tr
  int ktr = 0, ktc = 0;
  if (tid < 496){
    int t = tid;
    int r = (int)((sqrtf(8.0f*(float)t + 1.0f) + 1.0f)*0.5f);
    while (r*(r-1)/2 > t) --r;
    while ((r+1)*r/2 <= t) ++r;
    ktr = r; ktc = t - r*(r-1)/2;
  }
  const int i0 = ktr*8, j0k = ktc*8;

  // diagonal-tile elements (32 tiles x 36 elems = 1152), up to 3 per thread
  int dI[3], dJ[3];
  #pragma unroll
  for (int q = 0; q < 3; ++q){
    int e = tid + 512*q;
    if (e < 1152){
      int dt = e/36, e36 = e - dt*36;
      int r = (int)((sqrtf(8.0f*(float)e36 + 1.0f) - 1.0f)*0.5f);
      while (r*(r+1)/2 > e36) --r;
      while ((r+1)*(r+2)/2 <= e36) ++r;
      int c = e36 - r*(r+1)/2;
      dI[q] = dt*8 + r; dJ[q] = dt*8 + c;
    } else { dI[q] = -1; dJ[q] = 0; }
  }

  // ---- init state ----
  for (int i = tid; i < NP; i += BLOCK){
    zv[i] = 0.0f;
    sv[i] = 1.0f;
    lv[i] = (i < NI) ? 1.0f : 0.0f;
    psh[i] = Pg[b*NP + i];
    hsh[i] = Hg[i];
  }
  __syncthreads();

  for (int it = 0; it < NITER; ++it){
    // ---- A1: r1 = Q z (wave-per-row, 2 rows at a time) ----
    {
      int ib0 = wv*32;
      float z0l = zv[lane], z1l = zv[lane+64], z2l = zv[lane+128], z3l = zv[lane+192];
      for (int i = ib0; i < ib0 + 32; i += 2){
        const float* q0 = Qg + i*NP;
        const float* q1 = q0 + NP;
        float v0 = q0[lane]*z0l + q0[lane+64]*z1l + q0[lane+128]*z2l + q0[lane+192]*z3l;
        float v1 = q1[lane]*z0l + q1[lane+64]*z1l + q1[lane+128]*z2l + q1[lane+192]*z3l;
        #pragma unroll
        for (int m = 32; m >= 1; m >>= 1){ v0 += __shfl_xor(v0, m, 64); v1 += __shfl_xor(v1, m, 64); }
        if (lane == 0){ r1[i] = v0; r1[i+1] = v1; }
      }
    }
    // ---- A2: G^T lam partials ----
    {
      int i  = tid & 255;
      int k0 = (tid < 256) ? 0 : 127;
      int k1 = (tid < 256) ? 127 : NI;
      float acc = 0.0f;
      if (i < NH){
        const float* gp = G + k0*NH + i;
        #pragma unroll 4
        for (int k = k0; k < k1; ++k){ acc = fmaf(*gp, lv[k], acc); gp += NH; }
      }
      if (tid < 256) dsv[i] = acc; else dlv[i] = acc;
    }
    __syncthreads();
    // ---- A3: combine r1 ----
    if (tid < NP) r1[tid] = r1[tid] + psh[tid] + dsv[tid] + dlv[tid];
    // ---- B: r2 = G z + s - h (wave-per-row) ----
    {
      int kb = wv*32, ke = min(kb + 32, NI);
      float z0l = zv[lane], z1l = zv[lane+64], z2l = zv[lane+128];
      float z3l = (lane < 63) ? zv[lane+192] : 0.0f;
      for (int k = kb; k < ke; k += 2){
        const float* g0 = G + k*NH;
        const float* g1 = g0 + NH;
        float a3 = (lane < 63) ? g0[lane+192] : 0.0f;
        float b3 = (lane < 63) ? g1[lane+192] : 0.0f;
        float v0 = g0[lane]*z0l + g0[lane+64]*z1l + g0[lane+128]*z2l + a3*z3l;
        float v1 = g1[lane]*z0l + g1[lane+64]*z1l + g1[lane+128]*z2l + b3*z3l;
        #pragma unroll
        for (int m = 32; m >= 1; m >>= 1){ v0 += __shfl_xor(v0, m, 64); v1 += __shfl_xor(v1, m, 64); }
        if (lane == 0){
          r2[k]   = v0 + sv[k]   - hsh[k];
          r2[k+1] = v1 + sv[k+1] - hsh[k+1];
        }
      }
    }
    __syncthreads();
    // ---- C: mu, r3, d, w ----
    {
      float sl = (tid < NI) ? sv[tid]*lv[tid] : 0.0f;
      #pragma unroll
      for (int m = 32; m >= 1; m >>= 1) sl += __shfl_xor(sl, m, 64);
      if (lane == 0) misc[wv] = sl;
    }
    __syncthreads();
    if (tid == 0){
      float t = 0.0f;
      #pragma unroll
      for (int q = 0; q < 8; ++q) t += misc[q];
      misc[17] = SIGMA * (t * (1.0f/(float)NI));
    }
    __syncthreads();
    if (tid < NI){
      float sk = sv[tid], lk = lv[tid];
      float skg = fmaxf(sk, 1e-30f);                 // FTZ guard
      float r3k = sk*lk - misc[17];
      r3[tid] = r3k;
      dd[tid] = fminf(lk/skg, 1e24f);                // keep K build finite
      wwv[tid] = clampf((lk*r2[tid] - r3k)/skg, 1e30f);
    }
    __syncthreads();
    // ---- D0: K diagonal -> Jacobi equilibration scale dscv ----
    {
      int i  = tid & 255;
      int k0 = (tid < 256) ? 0 : 127;
      int k1 = (tid < 256) ? 127 : NI;
      float acc = 0.0f;
      if (i < NH){
        const float* gp = G + k0*NH + i;
        #pragma unroll 4
        for (int k = k0; k < k1; ++k){ float g = *gp; acc = fmaf(dd[k]*g, g, acc); gp += NH; }
      }
      if (tid < 256) dsv[i] = acc; else dlv[i] = acc;
    }
    __syncthreads();
    if (tid < NP){
      float diag = Qg[tid*NP + tid] + dsv[tid] + dlv[tid];
      dscv[tid] = rsqrtf(fmaxf(diag, 1e-12f));
    }
    __syncthreads();
    // ---- D: rhs = -(r1 + w @ G); scaled rhs~ = dsc * rhs -> yv ----
    {
      int i  = tid & 255;
      int k0 = (tid < 256) ? 0 : 127;
      int k1 = (tid < 256) ? 127 : NI;
      float acc = 0.0f;
      if (i < NH){
        const float* gp = G + k0*NH + i;
        #pragma unroll 4
        for (int k = k0; k < k1; ++k){ acc = fmaf(*gp, wwv[k], acc); gp += NH; }
      }
      if (tid < 256) dsv[i] = acc; else dlv[i] = acc;
    }
    __syncthreads();
    if (tid < NP) yv[tid] = -(r1[tid] + dsv[tid] + dlv[tid]) * dscv[tid];

    // ---- E: K~ = S(Q + G^T D G)S packed lower triangle in LDS ----
    // Scaled SPD with unit diagonal => all entries in [-1,1], |L~| <= 1: no overflow.
    float accT[64];
    if (tid < 496){
      #pragma unroll
      for (int r = 0; r < 8; ++r){
        float4 qa = *reinterpret_cast<const float4*>(&Qg[(i0+r)*NP + j0k]);
        float4 qb = *reinterpret_cast<const float4*>(&Qg[(i0+r)*NP + j0k + 4]);
        accT[r*8+0]=qa.x; accT[r*8+1]=qa.y; accT[r*8+2]=qa.z; accT[r*8+3]=qa.w;
        accT[r*8+4]=qb.x; accT[r*8+5]=qb.y; accT[r*8+6]=qb.z; accT[r*8+7]=qb.w;
      }
    }
    float accD[3];
    #pragma unroll
    for (int q = 0; q < 3; ++q) accD[q] = (dI[q] >= 0) ? Qg[dI[q]*NP + dJ[q]] : 0.0f;

    for (int c0 = 0; c0 < NP; c0 += KBCH){
      __syncthreads();
      { // stage sqrt(d[k]) * G[k][:] rows c0..c0+7 (zero-padded)
        int base = tid*4;
        int kk = base >> 8;
        int j  = base & 255;
        int krow = c0 + kk;
        float4 v; v.x = v.y = v.z = v.w = 0.0f;
        if (krow < NI){
          float sd = sqrtf(dd[krow]);
          const float* gr = G + krow*NH + j;
          v.x = gr[0]*sd;
          v.y = gr[1]*sd;
          v.z = gr[2]*sd;
          v.w = (j + 3 < NH) ? gr[3]*sd : 0.0f;
        }
        *reinterpret_cast<float4*>(&gb[base]) = v;
      }
      __syncthreads();
      #pragma unroll
      for (int kk = 0; kk < KBCH; ++kk){
        const float* gr = gb + kk*256;
        #pragma unroll
        for (int q = 0; q < 3; ++q)
          if (dI[q] >= 0) accD[q] = fmaf(gr[dI[q]], gr[dJ[q]], accD[q]);
        if (tid < 496){
          float4 a0 = *reinterpret_cast<const float4*>(&gr[i0]);
          float4 a1 = *reinterpret_cast<const float4*>(&gr[i0+4]);
          float4 b0 = *reinterpret_cast<const float4*>(&gr[j0k]);
          float4 b1 = *reinterpret_cast<const float4*>(&gr[j0k+4]);
          float gi[8] = {a0.x,a0.y,a0.z,a0.w,a1.x,a1.y,a1.z,a1.w};
          float gj[8] = {b0.x,b0.y,b0.z,b0.w,b1.x,b1.y,b1.z,b1.w};
          #pragma unroll
          for (int r = 0; r < 8; ++r){
            #pragma unroll
            for (int c = 0; c < 8; ++c) accT[r*8+c] = fmaf(gi[r], gj[c], accT[r*8+c]);
          }
        }
      }
    }
    __syncthreads();
    if (tid < 496){
      float sj[8];
      #pragma unroll
      for (int c = 0; c < 8; ++c) sj[c] = dscv[j0k + c];
      #pragma unroll
      for (int r = 0; r < 8; ++r){
        float sr = dscv[i0 + r];
        int rb = IDX(i0+r, j0k);
        float4 v0, v1;
        v0.x=accT[r*8+0]*sr*sj[0]; v0.y=accT[r*8+1]*sr*sj[1];
        v0.z=accT[r*8+2]*sr*sj[2]; v0.w=accT[r*8+3]*sr*sj[3];
        v1.x=accT[r*8+4]*sr*sj[4]; v1.y=accT[r*8+5]*sr*sj[5];
        v1.z=accT[r*8+6]*sr*sj[6]; v1.w=accT[r*8+7]*sr*sj[7];
        *reinterpret_cast<float4*>(&Kl[rb])   = v0;
        *reinterpret_cast<float4*>(&Kl[rb+4]) = v1;
      }
    }
    #pragma unroll
    for (int q = 0; q < 3; ++q)
      if (dI[q] >= 0) Kl[IDX(dI[q], dJ[q])] = accD[q]*dscv[dI[q]]*dscv[dJ[q]];
    __syncthreads();

    // ---- F: blocked Cholesky (NB=16) on K~ (row 255 = e255 stays inert) ----
    for (int pan = 0; pan < 16; ++pan){
      int j0 = pan*16;
      // 16x16 diag factor: single wave, all-register, shuffle-based.
      if (tid < 64){
        int r = lane & 15;
        int rb = IDX(j0 + r, j0);
        float a[16];
        #pragma unroll
        for (int qq = 0; qq < 4; ++qq){
          float4 v = *reinterpret_cast<const float4*>(&Kl[rb + 4*qq]);
          a[4*qq+0]=v.x; a[4*qq+1]=v.y; a[4*qq+2]=v.z; a[4*qq+3]=v.w;
        }
        #pragma unroll
        for (int j = 0; j < 16; ++j){
          float dj = __shfl(a[j], j);              // updated A[j][j] from lane j
          dj = (dj > 1e-8f) ? dj : 1e-8f;          // relative pivot floor (scrubs NaN)
          float piv = sqrtf(dj);
          float inv = 1.0f/piv;
          float lrj = clampf(a[j]*inv, 4.0f);      // |L~| <= 1 in exact arithmetic
          a[j] = (r == j) ? piv : lrj;
          if (lane == j) invd[j0+j] = inv;
          #pragma unroll
          for (int c = j+1; c < 16; ++c){
            float lcj = __shfl(a[j], c);           // L[c][j] from lane c
            a[c] = fmaf(-a[j], lcj, a[c]);
          }
        }
        if (lane < 16){
          #pragma unroll
          for (int c = 0; c < 16; ++c)
            if (c <= r) Kl[rb + c] = a[c];
        }
      }
      __syncthreads();
      int t0p = j0 + 16;
      if (t0p < NP){
        // panel solve: rows below diag block
        if (tid < NP - t0p){
          int i = t0p + tid;
          int rb = IDX(i, j0);
          float a[16];
          #pragma unroll
          for (int qq = 0; qq < 4; ++qq){
            float4 v = *reinterpret_cast<const float4*>(&Kl[rb + 4*qq]);
            a[4*qq+0]=v.x; a[4*qq+1]=v.y; a[4*qq+2]=v.z; a[4*qq+3]=v.w;
          }
          #pragma unroll
          for (int c = 0; c < 16; ++c){
            float v = a[c];
            int cb = IDX(j0+c, j0);
            #pragma unroll
            for (int k = 0; k < 16; ++k){ if (k < c) v -= a[k]*Kl[cb + k]; }
            a[c] = clampf(v * invd[j0+c], 4.0f);   // |L~| <= 1 exact; clamp junk
          }
          #pragma unroll
          for (int qq = 0; qq < 4; ++qq){
            float4 v; v.x=a[4*qq]; v.y=a[4*qq+1]; v.z=a[4*qq+2]; v.w=a[4*qq+3];
            *reinterpret_cast<float4*>(&Kl[rb + 4*qq]) = v;
          }
        }
        __syncthreads();
        // trailing update A22 -= L21 L21^T
        // register-lean: Lc[8] per k-slice, Li streamed one float4 per row
        // (peak live ~120 regs vs ~160 in the 2D-tile version; same LDS traffic)
        int nt = NP - t0p;
        int ntr = nt >> 3;
        int offt = ntr*(ntr-1)/2;
        for (int tt = tid; tt < offt; tt += BLOCK){
          int r = (int)((sqrtf(8.0f*(float)tt + 1.0f) + 1.0f)*0.5f);
          while (r*(r-1)/2 > tt) --r;
          while ((r+1)*r/2 <= tt) ++r;
          int c = tt - r*(r-1)/2;
          int ri = t0p + r*8, rj = t0p + c*8;
          int ib[8], jb[8];
          #pragma unroll
          for (int q = 0; q < 8; ++q){ ib[q] = IDX(ri+q, j0); jb[q] = IDX(rj+q, j0); }
          float acc[64];
          #pragma unroll
          for (int q = 0; q < 64; ++q) acc[q] = 0.0f;
          #pragma unroll
          for (int ks = 0; ks < 4; ++ks){
            float4 Lc[8];
            #pragma unroll
            for (int q = 0; q < 8; ++q) Lc[q] = *reinterpret_cast<const float4*>(&Kl[jb[q] + 4*ks]);
            #pragma unroll
            for (int rr = 0; rr < 8; ++rr){
              float4 Li = *reinterpret_cast<const float4*>(&Kl[ib[rr] + 4*ks]);
              #pragma unroll
              for (int cc = 0; cc < 8; ++cc){
                float v = acc[rr*8+cc];
                v = fmaf(Li.x, Lc[cc].x, v);
                v = fmaf(Li.y, Lc[cc].y, v);
                v = fmaf(Li.z, Lc[cc].z, v);
                v = fmaf(Li.w, Lc[cc].w, v);
                acc[rr*8+cc] = v;
              }
            }
          }
          #pragma unroll
          for (int rr = 0; rr < 8; ++rr){
            int rb2 = IDX(ri+rr, rj);
            float4 v0 = *reinterpret_cast<const float4*>(&Kl[rb2]);
            float4 v1 = *reinterpret_cast<const float4*>(&Kl[rb2+4]);
            v0.x -= acc[rr*8+0]; v0.y -= acc[rr*8+1]; v0.z -= acc[rr*8+2]; v0.w -= acc[rr*8+3];
            v1.x -= acc[rr*8+4]; v1.y -= acc[rr*8+5]; v1.z -= acc[rr*8+6]; v1.w -= acc[rr*8+7];
            *reinterpret_cast<float4*>(&Kl[rb2])   = v0;
            *reinterpret_cast<float4*>(&Kl[rb2+4]) = v1;
          }
        }
        int nde = ntr*36;
        for (int e = tid; e < nde; e += BLOCK){
          int dt = e/36, e36 = e - dt*36;
          int rr = (int)((sqrtf(8.0f*(float)e36 + 1.0f) - 1.0f)*0.5f);
          while (rr*(rr+1)/2 > e36) --rr;
          while ((rr+1)*(rr+2)/2 <= e36) ++rr;
          int cc = e36 - rr*(rr+1)/2;
          int i  = t0p + dt*8 + rr;
          int jc = t0p + dt*8 + cc;
          int ri2 = IDX(i, j0), rj2 = IDX(jc, j0);
          float acc = 0.0f;
          #pragma unroll
          for (int ks = 0; ks < 4; ++ks){
            float4 av = *reinterpret_cast<const float4*>(&Kl[ri2 + 4*ks]);
            float4 bv = *reinterpret_cast<const float4*>(&Kl[rj2 + 4*ks]);
            acc = fmaf(av.x, bv.x, acc); acc = fmaf(av.y, bv.y, acc);
            acc = fmaf(av.z, bv.z, acc); acc = fmaf(av.w, bv.w, acc);
          }
          Kl[IDX(i, jc)] -= acc;
        }
      }
      __syncthreads();
    }

    // ---- G: forward solve L y = rhs~ (in yv) ----
    for (int pan = 0; pan < 16; ++pan){
      int j0 = pan*16;
      if (tid < 64){
        int r = lane & 15;
        int rb = IDX(j0 + r, j0);
        float l[16];
        #pragma unroll
        for (int qq = 0; qq < 4; ++qq){
          float4 v = *reinterpret_cast<const float4*>(&Kl[rb + 4*qq]);
          l[4*qq+0]=v.x; l[4*qq+1]=v.y; l[4*qq+2]=v.z; l[4*qq+3]=v.w;
        }
        float y   = yv[j0 + r];
        float miv = invd[j0 + r];
        #pragma unroll
        for (int j = 0; j < 16; ++j){
          float t = __shfl(y, j) * __shfl(miv, j);   // final y_j
          if (r == j) y = t;
          else if (r > j) y = fmaf(-l[j], t, y);
        }
        if (lane < 16) yv[j0 + r] = y;
      }
      __syncthreads();
      int t0p = j0 + 16;
      if (t0p < NP && tid < NP - t0p){
        int i = t0p + tid;
        int rb = IDX(i, j0);
        float acc = yv[i];
        #pragma unroll
        for (int k = 0; k < 16; ++k) acc -= Kl[rb + k]*yv[j0+k];
        yv[i] = acc;
      }
      __syncthreads();
    }
    // ---- H: back solve L^T dz~ = y (in yv) ----
    for (int pan = 15; pan >= 0; --pan){
      int j0 = pan*16;
      if (tid < 64){
        int r = lane & 15;
        float col[16];
        #pragma unroll
        for (int j = 0; j < 16; ++j) col[j] = Kl[IDX(j0 + j, j0) + r];  // L[j0+j][j0+r]
        float y   = yv[j0 + r];
        float miv = invd[j0 + r];
        #pragma unroll
        for (int j = 15; j >= 0; --j){
          float t = __shfl(y, j) * __shfl(miv, j);   // dz~_j
          if (r == j) y = t;
          else if (r < j) y = fmaf(-col[j], t, y);
        }
        if (lane < 16) yv[j0 + r] = y;
      }
      __syncthreads();
      if (j0 > 0 && tid < j0){
        int i = tid;
        float acc = yv[i];
        #pragma unroll
        for (int k = 0; k < 16; ++k) acc -= Kl[IDX(j0+k, i)]*yv[j0+k];
        yv[i] = acc;
      }
      __syncthreads();
    }
    // ---- unscale: dz = S dz~ ----
    if (tid < NP) yv[tid] = clampf(yv[tid]*dscv[tid], 1e30f);
    __syncthreads();

    // ---- I: ds = -r2 - dz @ G^T (wave-per-row) ----
    {
      int kb = wv*32, ke = min(kb + 32, NI);
      float z0l = yv[lane], z1l = yv[lane+64], z2l = yv[lane+128];
      float z3l = (lane < 63) ? yv[lane+192] : 0.0f;
      for (int k = kb; k < ke; k += 2){
        const float* g0 = G + k*NH;
        const float* g1 = g0 + NH;
        float a3 = (lane < 63) ? g0[lane+192] : 0.0f;
        float b3 = (lane < 63) ? g1[lane+192] : 0.0f;
        float v0 = g0[lane]*z0l + g0[lane+64]*z1l + g0[lane+128]*z2l + a3*z3l;
        float v1 = g1[lane]*z0l + g1[lane+64]*z1l + g1[lane+128]*z2l + b3*z3l;
        #pragma unroll
        for (int m = 32; m >= 1; m >>= 1){ v0 += __shfl_xor(v0, m, 64); v1 += __shfl_xor(v1, m, 64); }
        if (lane == 0){
          dsv[k]   = clampf(-r2[k]   - v0, 1e30f);
          dsv[k+1] = clampf(-r2[k+1] - v1, 1e30f);
        }
      }
    }
    __syncthreads();
    // ---- J: dlam, alpha ----
    float loc = 1e10f;
    if (tid < NI){
      float dsk = dsv[tid];
      float skg = fmaxf(sv[tid], 1e-30f);
      float dlk = clampf((-r3[tid] - lv[tid]*dsk)/skg, 1e30f);
      dlv[tid] = dlk;
      if (dsk < 0.0f) loc = fminf(loc, -sv[tid]/dsk);
      if (dlk < 0.0f) loc = fminf(loc, -lv[tid]/dlk);
    }
    #pragma unroll
    for (int m = 32; m >= 1; m >>= 1) loc = fminf(loc, __shfl_xor(loc, m, 64));
    if (lane == 0) misc[wv] = loc;
    __syncthreads();
    if (tid == 0){
      float mn = 1e10f;
      #pragma unroll
      for (int q = 0; q < 8; ++q) mn = fminf(mn, misc[q]);
      misc[16] = fminf(1.0f, 0.99f*mn);
    }
    __syncthreads();
    {
      float alpha = misc[16];
      if (tid < NP) zv[tid] += alpha*yv[tid];
      if (tid < NI){
        sv[tid] += alpha*dsv[tid];
        lv[tid] += alpha*dlv[tid];
      }
    }
    __syncthreads();
  }

  if (tid < NFEAT) out[b*NFEAT + tid] = zv[tid];
}

extern "C" void kernel_launch(void* const* d_in, const int* in_sizes, int n_in,
                              void* d_out, int out_size, void* d_ws, size_t ws_size,
                              hipStream_t stream)
{
  const float* x    = (const float*)d_in[0];
  const float* W    = (const float*)d_in[1];
  const float* bias = (const float*)d_in[2];
  const float* L    = (const float*)d_in[3];
  const float* G    = (const float*)d_in[4];
  const float* z0   = (const float*)d_in[5];
  const float* s0   = (const float*)d_in[6];
  float* out = (float*)d_out;

  float* ws = (float*)d_ws;
  float* Qg = ws;               // 65536 floats
  float* Pg = Qg + 65536;       // 32768
  float* Hg = Pg + 32768;       // 256

  hipLaunchKernelGGL(k_setupQ, dim3(NP),     dim3(NP), 0, stream, L, Qg);
  hipLaunchKernelGGL(k_setupP, dim3(NBATCH), dim3(NP), 0, stream, x, W, bias, Pg);
  hipLaunchKernelGGL(k_setupH, dim3(1),      dim3(NP), 0, stream, G, z0, s0, Hg);

  hipFuncSetAttribute(reinterpret_cast<const void*>(qp_kernel),
                      hipFuncAttributeMaxDynamicSharedMemorySize, SMEM_BYTES);
  hipLaunchKernelGGL(qp_kernel, dim3(NBATCH), dim3(BLOCK), SMEM_BYTES, stream,
                     Qg, G, Pg, Hg, out);
}

// Round 6
// 14370.056 us; speedup vs baseline: 2.6357x; 2.5098x over previous
//
#include <hip/hip_runtime.h>
#include <math.h>

#define NFEAT 128
#define NH 255
#define NP 256
#define NI 254
#define NBATCH 128
#define EPSQ 1e-4f
#define NITER 20
#define SIGMA 0.1f
#define BLOCK 512
#define KBCH 8
#define KLSIZE 33280   /* packed lower triangle, rows padded to 4-float alignment */
#define SMEM_FLOATS (KLSIZE + KBCH*256 + 15*256 + 64)
#define SMEM_BYTES (SMEM_FLOATS*4)

// padded packed lower-triangle index: row i starts at 4*(a+1)*(2a+b), a=i>>2, b=i&3
__device__ __forceinline__ int IDX(int i, int j){
  int a = i >> 2, bb = i & 3;
  return 4*(a+1)*(2*a + bb) + j;
}
__device__ __forceinline__ float clampf(float x, float m){
  // also scrubs NaN -> -m (fmaxf/fminf return the non-NaN operand)
  return fminf(fmaxf(x, -m), m);
}

// ---------------- setup kernels (read L/W directly; minimal workspace) ----------------
__global__ void k_setupQ(const float* __restrict__ L, float* __restrict__ Q){
  int i = blockIdx.x, j = threadIdx.x;
  float acc;
  if (i < NH && j < NH){
    int kmax = (i < j) ? i : j;
    acc = 0.0f;
    for (int k = 0; k <= kmax; ++k) acc = fmaf(L[i*NH + k], L[j*NH + k], acc);
    if (i == j) acc += EPSQ;
  } else {
    acc = (i == j) ? 1.0f : 0.0f;   // padded row/col 255 = e255
  }
  Q[i*NP + j] = acc;
}
__global__ void k_setupP(const float* __restrict__ x, const float* __restrict__ W,
                         const float* __restrict__ bias, float* __restrict__ P){
  int b = blockIdx.x, j = threadIdx.x;
  float acc = 0.0f;
  if (j < NH){
    acc = bias[j];
    for (int f = 0; f < NFEAT; ++f) acc = fmaf(x[b*NFEAT + f], W[j*NFEAT + f], acc);
  }
  P[b*NP + j] = acc;
}
__global__ void k_setupH(const float* __restrict__ G, const float* __restrict__ z0,
                         const float* __restrict__ s0, float* __restrict__ H){
  int k = threadIdx.x;
  float acc = 0.0f;
  if (k < NI){
    acc = s0[k];
    for (int i = 0; i < NH; ++i) acc = fmaf(G[k*NH + i], z0[i], acc);
  }
  H[k] = acc;
}

// ---------------- main QP kernel: one block per batch row ----------------
// Spill-free by construction: all hot-loop live sets kept < ~110 VGPR so even the
// observed 128-VGPR cap cannot force scratch traffic (rounds 3-5: accT[64] lived in
// scratch -> 10.7 GB/dispatch of spill writes, VALUBusy 2%). Attributes kept as a
// secondary lever (512 threads = 8 waves = 2 waves/SIMD at 1 block/CU).
__global__ void
__attribute__((amdgpu_flat_work_group_size(512, 512), amdgpu_waves_per_eu(2, 2)))
qp_kernel(
    const float* __restrict__ Qg, const float* __restrict__ G,
    const float* __restrict__ Pg, const float* __restrict__ Hg,
    float* __restrict__ out)
{
  extern __shared__ float sm[];
  float* Kl   = sm;                 // 33280
  float* gb   = Kl + KLSIZE;        // KBCH*256
  float* zv   = gb + KBCH*256;
  float* sv   = zv + NP;
  float* lv   = sv + NP;
  float* psh  = lv + NP;
  float* hsh  = psh + NP;
  float* r1   = hsh + NP;
  float* r2   = r1 + NP;
  float* r3   = r2 + NP;
  float* dd   = r3 + NP;
  float* wwv  = dd + NP;
  float* dsv  = wwv + NP;
  float* dlv  = dsv + NP;
  float* yv   = dlv + NP;
  float* invd = yv + NP;
  float* dscv = invd + NP;
  float* misc = dscv + NP;          // 64

  const int tid  = threadIdx.x;
  const int lane = tid & 63;
  const int wv   = tid >> 6;
  const int b    = blockIdx.x;

  // ---- zero ALL of LDS: padding slots of the packed triangle stay 0 forever,
  // so every float4 over-read is benign by construction ----
  for (int i = tid; i < SMEM_FLOATS; i += BLOCK) sm[i] = 0.0f;
  __syncthreads();

  // ---- static mappings ----
  // off-diagonal 8x8 K tiles: tid<496 -> (tr,tc), tr in 1..31, tc<tr
  int ktr = 0, ktc = 0;
  if (tid < 496){
    int t = tid;
    int r = (int)((sqrtf(8.0f*(float)t + 1.0f) + 1.0f)*0.5f);
    while (r*(r-1)/2 > t) --r;
    while ((r+1)*r/2 <= t) ++r;
    ktr = r; ktc = t - r*(r-1)/2;
  }
  const int i0 = ktr*8, j0k = ktc*8;

  // diagonal-tile elements (32 tiles x 36 elems = 1152), up to 3 per thread
  int dI[3], dJ[3];
  #pragma unroll
  for (int q = 0; q < 3; ++q){
    int e = tid + 512*q;
    if (e < 1152){
      int dt = e/36, e36 = e - dt*36;
      int r = (int)((sqrtf(8.0f*(float)e36 + 1.0f) - 1.0f)*0.5f);
      while (r*(r+1)/2 > e36) --r;
      while ((r+1)*(r+2)/2 <= e36) ++r;
      int c = e36 - r*(r+1)/2;
      dI[q] = dt*8 + r; dJ[q] = dt*8 + c;
    } else { dI[q] = -1; dJ[q] = 0; }
  }

  // ---- init state ----
  for (int i = tid; i < NP; i += BLOCK){
    zv[i] = 0.0f;
    sv[i] = 1.0f;
    lv[i] = (i < NI) ? 1.0f : 0.0f;
    psh[i] = Pg[b*NP + i];
    hsh[i] = Hg[i];
  }
  __syncthreads();

  for (int it = 0; it < NITER; ++it){
    // ---- A1: r1 = Q z (wave-per-row, 2 rows at a time) ----
    {
      int ib0 = wv*32;
      float z0l = zv[lane], z1l = zv[lane+64], z2l = zv[lane+128], z3l = zv[lane+192];
      for (int i = ib0; i < ib0 + 32; i += 2){
        const float* q0 = Qg + i*NP;
        const float* q1 = q0 + NP;
        float v0 = q0[lane]*z0l + q0[lane+64]*z1l + q0[lane+128]*z2l + q0[lane+192]*z3l;
        float v1 = q1[lane]*z0l + q1[lane+64]*z1l + q1[lane+128]*z2l + q1[lane+192]*z3l;
        #pragma unroll
        for (int m = 32; m >= 1; m >>= 1){ v0 += __shfl_xor(v0, m, 64); v1 += __shfl_xor(v1, m, 64); }
        if (lane == 0){ r1[i] = v0; r1[i+1] = v1; }
      }
    }
    // ---- A2: G^T lam partials ----
    {
      int i  = tid & 255;
      int k0 = (tid < 256) ? 0 : 127;
      int k1 = (tid < 256) ? 127 : NI;
      float acc = 0.0f;
      if (i < NH){
        const float* gp = G + k0*NH + i;
        #pragma unroll 4
        for (int k = k0; k < k1; ++k){ acc = fmaf(*gp, lv[k], acc); gp += NH; }
      }
      if (tid < 256) dsv[i] = acc; else dlv[i] = acc;
    }
    __syncthreads();
    // ---- A3: combine r1 ----
    if (tid < NP) r1[tid] = r1[tid] + psh[tid] + dsv[tid] + dlv[tid];
    // ---- B: r2 = G z + s - h (wave-per-row) ----
    {
      int kb = wv*32, ke = min(kb + 32, NI);
      float z0l = zv[lane], z1l = zv[lane+64], z2l = zv[lane+128];
      float z3l = (lane < 63) ? zv[lane+192] : 0.0f;
      for (int k = kb; k < ke; k += 2){
        const float* g0 = G + k*NH;
        const float* g1 = g0 + NH;
        float a3 = (lane < 63) ? g0[lane+192] : 0.0f;
        float b3 = (lane < 63) ? g1[lane+192] : 0.0f;
        float v0 = g0[lane]*z0l + g0[lane+64]*z1l + g0[lane+128]*z2l + a3*z3l;
        float v1 = g1[lane]*z0l + g1[lane+64]*z1l + g1[lane+128]*z2l + b3*z3l;
        #pragma unroll
        for (int m = 32; m >= 1; m >>= 1){ v0 += __shfl_xor(v0, m, 64); v1 += __shfl_xor(v1, m, 64); }
        if (lane == 0){
          r2[k]   = v0 + sv[k]   - hsh[k];
          r2[k+1] = v1 + sv[k+1] - hsh[k+1];
        }
      }
    }
    __syncthreads();
    // ---- C: mu, r3, d, w ----
    {
      float sl = (tid < NI) ? sv[tid]*lv[tid] : 0.0f;
      #pragma unroll
      for (int m = 32; m >= 1; m >>= 1) sl += __shfl_xor(sl, m, 64);
      if (lane == 0) misc[wv] = sl;
    }
    __syncthreads();
    if (tid == 0){
      float t = 0.0f;
      #pragma unroll
      for (int q = 0; q < 8; ++q) t += misc[q];
      misc[17] = SIGMA * (t * (1.0f/(float)NI));
    }
    __syncthreads();
    if (tid < NI){
      float sk = sv[tid], lk = lv[tid];
      float skg = fmaxf(sk, 1e-30f);                 // FTZ guard
      float r3k = sk*lk - misc[17];
      r3[tid] = r3k;
      dd[tid] = fminf(lk/skg, 1e24f);                // keep K build finite
      wwv[tid] = clampf((lk*r2[tid] - r3k)/skg, 1e30f);
    }
    __syncthreads();
    // ---- D0: K diagonal -> Jacobi equilibration scale dscv ----
    {
      int i  = tid & 255;
      int k0 = (tid < 256) ? 0 : 127;
      int k1 = (tid < 256) ? 127 : NI;
      float acc = 0.0f;
      if (i < NH){
        const float* gp = G + k0*NH + i;
        #pragma unroll 4
        for (int k = k0; k < k1; ++k){ float g = *gp; acc = fmaf(dd[k]*g, g, acc); gp += NH; }
      }
      if (tid < 256) dsv[i] = acc; else dlv[i] = acc;
    }
    __syncthreads();
    if (tid < NP){
      float diag = Qg[tid*NP + tid] + dsv[tid] + dlv[tid];
      dscv[tid] = rsqrtf(fmaxf(diag, 1e-12f));
    }
    __syncthreads();
    // ---- D: rhs = -(r1 + w @ G); scaled rhs~ = dsc * rhs -> yv ----
    {
      int i  = tid & 255;
      int k0 = (tid < 256) ? 0 : 127;
      int k1 = (tid < 256) ? 127 : NI;
      float acc = 0.0f;
      if (i < NH){
        const float* gp = G + k0*NH + i;
        #pragma unroll 4
        for (int k = k0; k < k1; ++k){ acc = fmaf(*gp, wwv[k], acc); gp += NH; }
      }
      if (tid < 256) dsv[i] = acc; else dlv[i] = acc;
    }
    __syncthreads();
    if (tid < NP) yv[tid] = -(r1[tid] + dsv[tid] + dlv[tid]) * dscv[tid];

    // ---- E: K~ = S(Q + G^T D G)S packed lower triangle in LDS ----
    // TWO PASSES of 4 rows x 8 cols per thread: accT[32] live (not 64) so the
    // whole phase fits a 128-VGPR budget with zero scratch. Staging runs twice
    // (G is L2-resident; cheap vs 10 GB of spill traffic it replaces).
    float accD[3];
    #pragma unroll
    for (int q = 0; q < 3; ++q) accD[q] = (dI[q] >= 0) ? Qg[dI[q]*NP + dJ[q]] : 0.0f;

    #pragma unroll 1
    for (int p = 0; p < 2; ++p){
      const int ri0 = i0 + 4*p;
      float accT[32];
      if (tid < 496){
        #pragma unroll
        for (int r = 0; r < 4; ++r){
          float4 qa = *reinterpret_cast<const float4*>(&Qg[(ri0+r)*NP + j0k]);
          float4 qb = *reinterpret_cast<const float4*>(&Qg[(ri0+r)*NP + j0k + 4]);
          accT[r*8+0]=qa.x; accT[r*8+1]=qa.y; accT[r*8+2]=qa.z; accT[r*8+3]=qa.w;
          accT[r*8+4]=qb.x; accT[r*8+5]=qb.y; accT[r*8+6]=qb.z; accT[r*8+7]=qb.w;
        }
      }
      for (int c0 = 0; c0 < NP; c0 += KBCH){
        __syncthreads();
        { // stage sqrt(d[k]) * G[k][:] rows c0..c0+7 (zero-padded)
          int base = tid*4;
          int kk = base >> 8;
          int j  = base & 255;
          int krow = c0 + kk;
          float4 v; v.x = v.y = v.z = v.w = 0.0f;
          if (krow < NI){
            float sd = sqrtf(dd[krow]);
            const float* gr = G + krow*NH + j;
            v.x = gr[0]*sd;
            v.y = gr[1]*sd;
            v.z = gr[2]*sd;
            v.w = (j + 3 < NH) ? gr[3]*sd : 0.0f;
          }
          *reinterpret_cast<float4*>(&gb[base]) = v;
        }
        __syncthreads();
        #pragma unroll
        for (int kk = 0; kk < KBCH; ++kk){
          const float* gr = gb + kk*256;
          if (p == 0){
            #pragma unroll
            for (int q = 0; q < 3; ++q)
              if (dI[q] >= 0) accD[q] = fmaf(gr[dI[q]], gr[dJ[q]], accD[q]);
          }
          if (tid < 496){
            float4 a0 = *reinterpret_cast<const float4*>(&gr[ri0]);
            float4 b0 = *reinterpret_cast<const float4*>(&gr[j0k]);
            float4 b1 = *reinterpret_cast<const float4*>(&gr[j0k+4]);
            float gi[4] = {a0.x,a0.y,a0.z,a0.w};
            float gj[8] = {b0.x,b0.y,b0.z,b0.w,b1.x,b1.y,b1.z,b1.w};
            #pragma unroll
            for (int r = 0; r < 4; ++r){
              #pragma unroll
              for (int c = 0; c < 8; ++c) accT[r*8+c] = fmaf(gi[r], gj[c], accT[r*8+c]);
            }
          }
        }
      }
      // store-back this pass's 4 rows (scaled); safe: next pass re-barriers
      // before touching gb, and Kl is disjoint from gb.
      if (tid < 496){
        #pragma unroll
        for (int r = 0; r < 4; ++r){
          float sr = dscv[ri0 + r];
          int rb = IDX(ri0+r, j0k);
          float4 v0, v1;
          v0.x=accT[r*8+0]*sr*dscv[j0k+0]; v0.y=accT[r*8+1]*sr*dscv[j0k+1];
          v0.z=accT[r*8+2]*sr*dscv[j0k+2]; v0.w=accT[r*8+3]*sr*dscv[j0k+3];
          v1.x=accT[r*8+4]*sr*dscv[j0k+4]; v1.y=accT[r*8+5]*sr*dscv[j0k+5];
          v1.z=accT[r*8+6]*sr*dscv[j0k+6]; v1.w=accT[r*8+7]*sr*dscv[j0k+7];
          *reinterpret_cast<float4*>(&Kl[rb])   = v0;
          *reinterpret_cast<float4*>(&Kl[rb+4]) = v1;
        }
      }
      if (p == 0){
        #pragma unroll
        for (int q = 0; q < 3; ++q)
          if (dI[q] >= 0) Kl[IDX(dI[q], dJ[q])] = accD[q]*dscv[dI[q]]*dscv[dJ[q]];
      }
    }
    __syncthreads();

    // ---- F: blocked Cholesky (NB=16) on K~ (row 255 = e255 stays inert) ----
    for (int pan = 0; pan < 16; ++pan){
      int j0 = pan*16;
      // 16x16 diag factor: single wave, all-register, shuffle-based.
      if (tid < 64){
        int r = lane & 15;
        int rb = IDX(j0 + r, j0);
        float a[16];
        #pragma unroll
        for (int qq = 0; qq < 4; ++qq){
          float4 v = *reinterpret_cast<const float4*>(&Kl[rb + 4*qq]);
          a[4*qq+0]=v.x; a[4*qq+1]=v.y; a[4*qq+2]=v.z; a[4*qq+3]=v.w;
        }
        #pragma unroll
        for (int j = 0; j < 16; ++j){
          float dj = __shfl(a[j], j);              // updated A[j][j] from lane j
          dj = (dj > 1e-8f) ? dj : 1e-8f;          // relative pivot floor (scrubs NaN)
          float piv = sqrtf(dj);
          float inv = 1.0f/piv;
          float lrj = clampf(a[j]*inv, 4.0f);      // |L~| <= 1 in exact arithmetic
          a[j] = (r == j) ? piv : lrj;
          if (lane == j) invd[j0+j] = inv;
          #pragma unroll
          for (int c = j+1; c < 16; ++c){
            float lcj = __shfl(a[j], c);           // L[c][j] from lane c
            a[c] = fmaf(-a[j], lcj, a[c]);
          }
        }
        if (lane < 16){
          #pragma unroll
          for (int c = 0; c < 16; ++c)
            if (c <= r) Kl[rb + c] = a[c];
        }
      }
      __syncthreads();
      int t0p = j0 + 16;
      if (t0p < NP){
        // panel solve: rows below diag block
        if (tid < NP - t0p){
          int i = t0p + tid;
          int rb = IDX(i, j0);
          float a[16];
          #pragma unroll
          for (int qq = 0; qq < 4; ++qq){
            float4 v = *reinterpret_cast<const float4*>(&Kl[rb + 4*qq]);
            a[4*qq+0]=v.x; a[4*qq+1]=v.y; a[4*qq+2]=v.z; a[4*qq+3]=v.w;
          }
          #pragma unroll
          for (int c = 0; c < 16; ++c){
            float v = a[c];
            int cb = IDX(j0+c, j0);
            #pragma unroll
            for (int k = 0; k < 16; ++k){ if (k < c) v -= a[k]*Kl[cb + k]; }
            a[c] = clampf(v * invd[j0+c], 4.0f);   // |L~| <= 1 exact; clamp junk
          }
          #pragma unroll
          for (int qq = 0; qq < 4; ++qq){
            float4 v; v.x=a[4*qq]; v.y=a[4*qq+1]; v.z=a[4*qq+2]; v.w=a[4*qq+3];
            *reinterpret_cast<float4*>(&Kl[rb + 4*qq]) = v;
          }
        }
        __syncthreads();
        // trailing update A22 -= L21 L21^T
        // register-lean: Lc[8] per k-slice, Li streamed; IDX recomputed inline
        // (no ib/jb arrays) -> live ~105 regs, fits the 128 budget.
        int nt = NP - t0p;
        int ntr = nt >> 3;
        int offt = ntr*(ntr-1)/2;
        for (int tt = tid; tt < offt; tt += BLOCK){
          int r = (int)((sqrtf(8.0f*(float)tt + 1.0f) + 1.0f)*0.5f);
          while (r*(r-1)/2 > tt) --r;
          while ((r+1)*r/2 <= tt) ++r;
          int c = tt - r*(r-1)/2;
          int ri = t0p + r*8, rj = t0p + c*8;
          float acc[64];
          #pragma unroll
          for (int q = 0; q < 64; ++q) acc[q] = 0.0f;
          #pragma unroll
          for (int ks = 0; ks < 4; ++ks){
            float4 Lc[8];
            #pragma unroll
            for (int q = 0; q < 8; ++q)
              Lc[q] = *reinterpret_cast<const float4*>(&Kl[IDX(rj+q, j0) + 4*ks]);
            #pragma unroll
            for (int rr = 0; rr < 8; ++rr){
              float4 Li = *reinterpret_cast<const float4*>(&Kl[IDX(ri+rr, j0) + 4*ks]);
              #pragma unroll
              for (int cc = 0; cc < 8; ++cc){
                float v = acc[rr*8+cc];
                v = fmaf(Li.x, Lc[cc].x, v);
                v = fmaf(Li.y, Lc[cc].y, v);
                v = fmaf(Li.z, Lc[cc].z, v);
                v = fmaf(Li.w, Lc[cc].w, v);
                acc[rr*8+cc] = v;
              }
            }
          }
          #pragma unroll
          for (int rr = 0; rr < 8; ++rr){
            int rb2 = IDX(ri+rr, rj);
            float4 v0 = *reinterpret_cast<const float4*>(&Kl[rb2]);
            float4 v1 = *reinterpret_cast<const float4*>(&Kl[rb2+4]);
            v0.x -= acc[rr*8+0]; v0.y -= acc[rr*8+1]; v0.z -= acc[rr*8+2]; v0.w -= acc[rr*8+3];
            v1.x -= acc[rr*8+4]; v1.y -= acc[rr*8+5]; v1.z -= acc[rr*8+6]; v1.w -= acc[rr*8+7];
            *reinterpret_cast<float4*>(&Kl[rb2])   = v0;
            *reinterpret_cast<float4*>(&Kl[rb2+4]) = v1;
          }
        }
        int nde = ntr*36;
        for (int e = tid; e < nde; e += BLOCK){
          int dt = e/36, e36 = e - dt*36;
          int rr = (int)((sqrtf(8.0f*(float)e36 + 1.0f) - 1.0f)*0.5f);
          while (rr*(rr+1)/2 > e36) --rr;
          while ((rr+1)*(rr+2)/2 <= e36) ++rr;
          int cc = e36 - rr*(rr+1)/2;
          int i  = t0p + dt*8 + rr;
          int jc = t0p + dt*8 + cc;
          int ri2 = IDX(i, j0), rj2 = IDX(jc, j0);
          float acc = 0.0f;
          #pragma unroll
          for (int ks = 0; ks < 4; ++ks){
            float4 av = *reinterpret_cast<const float4*>(&Kl[ri2 + 4*ks]);
            float4 bv = *reinterpret_cast<const float4*>(&Kl[rj2 + 4*ks]);
            acc = fmaf(av.x, bv.x, acc); acc = fmaf(av.y, bv.y, acc);
            acc = fmaf(av.z, bv.z, acc); acc = fmaf(av.w, bv.w, acc);
          }
          Kl[IDX(i, jc)] -= acc;
        }
      }
      __syncthreads();
    }

    // ---- G: forward solve L y = rhs~ (in yv) ----
    for (int pan = 0; pan < 16; ++pan){
      int j0 = pan*16;
      if (tid < 64){
        int r = lane & 15;
        int rb = IDX(j0 + r, j0);
        float l[16];
        #pragma unroll
        for (int qq = 0; qq < 4; ++qq){
          float4 v = *reinterpret_cast<const float4*>(&Kl[rb + 4*qq]);
          l[4*qq+0]=v.x; l[4*qq+1]=v.y; l[4*qq+2]=v.z; l[4*qq+3]=v.w;
        }
        float y   = yv[j0 + r];
        float miv = invd[j0 + r];
        #pragma unroll
        for (int j = 0; j < 16; ++j){
          float t = __shfl(y, j) * __shfl(miv, j);   // final y_j
          if (r == j) y = t;
          else if (r > j) y = fmaf(-l[j], t, y);
        }
        if (lane < 16) yv[j0 + r] = y;
      }
      __syncthreads();
      int t0p = j0 + 16;
      if (t0p < NP && tid < NP - t0p){
        int i = t0p + tid;
        int rb = IDX(i, j0);
        float acc = yv[i];
        #pragma unroll
        for (int k = 0; k < 16; ++k) acc -= Kl[rb + k]*yv[j0+k];
        yv[i] = acc;
      }
      __syncthreads();
    }
    // ---- H: back solve L^T dz~ = y (in yv) ----
    for (int pan = 15; pan >= 0; --pan){
      int j0 = pan*16;
      if (tid < 64){
        int r = lane & 15;
        float col[16];
        #pragma unroll
        for (int j = 0; j < 16; ++j) col[j] = Kl[IDX(j0 + j, j0) + r];  // L[j0+j][j0+r]
        float y   = yv[j0 + r];
        float miv = invd[j0 + r];
        #pragma unroll
        for (int j = 15; j >= 0; --j){
          float t = __shfl(y, j) * __shfl(miv, j);   // dz~_j
          if (r == j) y = t;
          else if (r < j) y = fmaf(-col[j], t, y);
        }
        if (lane < 16) yv[j0 + r] = y;
      }
      __syncthreads();
      if (j0 > 0 && tid < j0){
        int i = tid;
        float acc = yv[i];
        #pragma unroll
        for (int k = 0; k < 16; ++k) acc -= Kl[IDX(j0+k, i)]*yv[j0+k];
        yv[i] = acc;
      }
      __syncthreads();
    }
    // ---- unscale: dz = S dz~ ----
    if (tid < NP) yv[tid] = clampf(yv[tid]*dscv[tid], 1e30f);
    __syncthreads();

    // ---- I: ds = -r2 - dz @ G^T (wave-per-row) ----
    {
      int kb = wv*32, ke = min(kb + 32, NI);
      float z0l = yv[lane], z1l = yv[lane+64], z2l = yv[lane+128];
      float z3l = (lane < 63) ? yv[lane+192] : 0.0f;
      for (int k = kb; k < ke; k += 2){
        const float* g0 = G + k*NH;
        const float* g1 = g0 + NH;
        float a3 = (lane < 63) ? g0[lane+192] : 0.0f;
        float b3 = (lane < 63) ? g1[lane+192] : 0.0f;
        float v0 = g0[lane]*z0l + g0[lane+64]*z1l + g0[lane+128]*z2l + a3*z3l;
        float v1 = g1[lane]*z0l + g1[lane+64]*z1l + g1[lane+128]*z2l + b3*z3l;
        #pragma unroll
        for (int m = 32; m >= 1; m >>= 1){ v0 += __shfl_xor(v0, m, 64); v1 += __shfl_xor(v1, m, 64); }
        if (lane == 0){
          dsv[k]   = clampf(-r2[k]   - v0, 1e30f);
          dsv[k+1] = clampf(-r2[k+1] - v1, 1e30f);
        }
      }
    }
    __syncthreads();
    // ---- J: dlam, alpha ----
    float loc = 1e10f;
    if (tid < NI){
      float dsk = dsv[tid];
      float skg = fmaxf(sv[tid], 1e-30f);
      float dlk = clampf((-r3[tid] - lv[tid]*dsk)/skg, 1e30f);
      dlv[tid] = dlk;
      if (dsk < 0.0f) loc = fminf(loc, -sv[tid]/dsk);
      if (dlk < 0.0f) loc = fminf(loc, -lv[tid]/dlk);
    }
    #pragma unroll
    for (int m = 32; m >= 1; m >>= 1) loc = fminf(loc, __shfl_xor(loc, m, 64));
    if (lane == 0) misc[wv] = loc;
    __syncthreads();
    if (tid == 0){
      float mn = 1e10f;
      #pragma unroll
      for (int q = 0; q < 8; ++q) mn = fminf(mn, misc[q]);
      misc[16] = fminf(1.0f, 0.99f*mn);
    }
    __syncthreads();
    {
      float alpha = misc[16];
      if (tid < NP) zv[tid] += alpha*yv[tid];
      if (tid < NI){
        sv[tid] += alpha*dsv[tid];
        lv[tid] += alpha*dlv[tid];
      }
    }
    __syncthreads();
  }

  if (tid < NFEAT) out[b*NFEAT + tid] = zv[tid];
}

extern "C" void kernel_launch(void* const* d_in, const int* in_sizes, int n_in,
                              void* d_out, int out_size, void* d_ws, size_t ws_size,
                              hipStream_t stream)
{
  const float* x    = (const float*)d_in[0];
  const float* W    = (const float*)d_in[1];
  const float* bias = (const float*)d_in[2];
  const float* L    = (const float*)d_in[3];
  const float* G    = (const float*)d_in[4];
  const float* z0   = (const float*)d_in[5];
  const float* s0   = (const float*)d_in[6];
  float* out = (float*)d_out;

  float* ws = (float*)d_ws;
  float* Qg = ws;               // 65536 floats
  float* Pg = Qg + 65536;       // 32768
  float* Hg = Pg + 32768;       // 256

  hipLaunchKernelGGL(k_setupQ, dim3(NP),     dim3(NP), 0, stream, L, Qg);
  hipLaunchKernelGGL(k_setupP, dim3(NBATCH), dim3(NP), 0, stream, x, W, bias, Pg);
  hipLaunchKernelGGL(k_setupH, dim3(1),      dim3(NP), 0, stream, G, z0, s0, Hg);

  hipFuncSetAttribute(reinterpret_cast<const void*>(qp_kernel),
                      hipFuncAttributeMaxDynamicSharedMemorySize, SMEM_BYTES);
  hipLaunchKernelGGL(qp_kernel, dim3(NBATCH), dim3(BLOCK), SMEM_BYTES, stream,
                     Qg, G, Pg, Hg, out);
}